// Round 1
// baseline (5436.938 us; speedup 1.0000x reference)
//
#include <hip/hip_runtime.h>
#include <hip/hip_bf16.h>

#define N_NODES 100000
#define N_EDGES 3200000
#define IN_CH   256
#define OUT_CH  128

// ---------------- GEMM: h = x @ W + b  ([N,256] @ [256,128]) ----------------
// Block: 256 threads, tile 32 rows x 128 cols. Each thread: 4 rows x 4 cols.
// K staged in chunks of 64: xs = 8KB, ws = 32KB LDS.
#define TM 32
#define KC 64

__global__ __launch_bounds__(256) void gemm_bias_kernel(
    const float* __restrict__ x, const float* __restrict__ W,
    const float* __restrict__ b, float* __restrict__ h) {
  __shared__ float xs[TM][KC];       // 8 KB
  __shared__ float ws[KC][OUT_CH];   // 32 KB

  const int tid = threadIdx.x;
  const int row0 = blockIdx.x * TM;
  const int tx = tid & 31;   // col group: cols tx*4 .. tx*4+3
  const int ty = tid >> 5;   // 0..7 -> rows ty*4 .. ty*4+3

  float4 acc[4];
  const float4 bias = reinterpret_cast<const float4*>(b)[tx];
#pragma unroll
  for (int i = 0; i < 4; ++i) acc[i] = bias;

  for (int kk = 0; kk < IN_CH; kk += KC) {
    // stage x tile: 32 rows x 64 k = 512 float4, 2 per thread
#pragma unroll
    for (int f = tid; f < TM * KC / 4; f += 256) {
      int r = f >> 4, kq = f & 15;
      float4 v = reinterpret_cast<const float4*>(
          x + (size_t)(row0 + r) * IN_CH + kk)[kq];
      reinterpret_cast<float4*>(&xs[r][0])[kq] = v;
    }
    // stage W tile: 64 k x 128 n = 2048 float4, 8 per thread
#pragma unroll
    for (int f = tid; f < KC * OUT_CH / 4; f += 256) {
      int k = f >> 5, nq = f & 31;
      float4 v = reinterpret_cast<const float4*>(
          W + (size_t)(kk + k) * OUT_CH)[nq];
      reinterpret_cast<float4*>(&ws[k][0])[nq] = v;
    }
    __syncthreads();

#pragma unroll 8
    for (int k = 0; k < KC; ++k) {
      float4 wv = reinterpret_cast<float4*>(&ws[k][0])[tx];
#pragma unroll
      for (int i = 0; i < 4; ++i) {
        float xv = xs[ty * 4 + i][k];
        acc[i].x += xv * wv.x;
        acc[i].y += xv * wv.y;
        acc[i].z += xv * wv.z;
        acc[i].w += xv * wv.w;
      }
    }
    __syncthreads();
  }

#pragma unroll
  for (int i = 0; i < 4; ++i) {
    reinterpret_cast<float4*>(h + (size_t)(row0 + ty * 4 + i) * OUT_CH)[tx] =
        acc[i];
  }
}

// ---------------- Scatter: out[row[e]] += val[e] * h[col[e]] ----------------
// 32 lanes per edge; each lane owns one float4 (4 channels) of the 128.
__global__ __launch_bounds__(256) void scatter_kernel(
    const float* __restrict__ h, const int* __restrict__ erow,
    const int* __restrict__ ecol, const float* __restrict__ eval,
    float* __restrict__ out) {
  const long long gid = (long long)blockIdx.x * blockDim.x + threadIdx.x;
  const int e = (int)(gid >> 5);
  const int lane = (int)(gid & 31);
  if (e >= N_EDGES) return;

  const int r = erow[e];
  const int c = ecol[e];
  const float v = eval[e];

  const float4 g = reinterpret_cast<const float4*>(h + (size_t)c * OUT_CH)[lane];
  float* o = out + (size_t)r * OUT_CH + lane * 4;
  atomicAdd(o + 0, v * g.x);
  atomicAdd(o + 1, v * g.y);
  atomicAdd(o + 2, v * g.z);
  atomicAdd(o + 3, v * g.w);
}

extern "C" void kernel_launch(void* const* d_in, const int* in_sizes, int n_in,
                              void* d_out, int out_size, void* d_ws,
                              size_t ws_size, hipStream_t stream) {
  const float* x    = (const float*)d_in[0];
  const float* W    = (const float*)d_in[1];
  const float* b    = (const float*)d_in[2];
  const int* erow   = (const int*)d_in[3];
  const int* ecol   = (const int*)d_in[4];
  const float* eval = (const float*)d_in[5];
  float* out = (float*)d_out;
  float* h   = (float*)d_ws;  // needs N_NODES*OUT_CH*4 = 51.2 MB

  // 1) h = x @ W + b
  gemm_bias_kernel<<<N_NODES / TM, 256, 0, stream>>>(x, W, b, h);

  // 2) zero the output (harness poisons it)
  hipMemsetAsync(d_out, 0, (size_t)out_size * sizeof(float), stream);

  // 3) scatter-add
  const long long total = (long long)N_EDGES * 32;
  const int blocks = (int)((total + 255) / 256);
  scatter_kernel<<<blocks, 256, 0, stream>>>(h, erow, ecol, eval, out);
}

// Round 2
// 852.806 us; speedup vs baseline: 6.3754x; 6.3754x over previous
//
#include <hip/hip_runtime.h>
#include <hip/hip_bf16.h>

#define N_NODES 100000
#define N_EDGES 3200000
#define IN_CH   256
#define OUT_CH  128

// ---------------- GEMM: h = x @ W + b  ([N,256] @ [256,128]) ----------------
#define TM 32
#define KC 64

__global__ __launch_bounds__(256) void gemm_bias_kernel(
    const float* __restrict__ x, const float* __restrict__ W,
    const float* __restrict__ b, float* __restrict__ h) {
  __shared__ float xs[TM][KC];       // 8 KB
  __shared__ float ws[KC][OUT_CH];   // 32 KB

  const int tid = threadIdx.x;
  const int row0 = blockIdx.x * TM;
  const int tx = tid & 31;   // cols tx*4 .. tx*4+3
  const int ty = tid >> 5;   // rows ty*4 .. ty*4+3

  float4 acc[4];
  const float4 bias = reinterpret_cast<const float4*>(b)[tx];
#pragma unroll
  for (int i = 0; i < 4; ++i) acc[i] = bias;

  for (int kk = 0; kk < IN_CH; kk += KC) {
#pragma unroll
    for (int f = tid; f < TM * KC / 4; f += 256) {
      int r = f >> 4, kq = f & 15;
      float4 v = reinterpret_cast<const float4*>(
          x + (size_t)(row0 + r) * IN_CH + kk)[kq];
      reinterpret_cast<float4*>(&xs[r][0])[kq] = v;
    }
#pragma unroll
    for (int f = tid; f < KC * OUT_CH / 4; f += 256) {
      int k = f >> 5, nq = f & 31;
      float4 v = reinterpret_cast<const float4*>(
          W + (size_t)(kk + k) * OUT_CH)[nq];
      reinterpret_cast<float4*>(&ws[k][0])[nq] = v;
    }
    __syncthreads();

#pragma unroll 8
    for (int k = 0; k < KC; ++k) {
      float4 wv = reinterpret_cast<float4*>(&ws[k][0])[tx];
#pragma unroll
      for (int i = 0; i < 4; ++i) {
        float xv = xs[ty * 4 + i][k];
        acc[i].x += xv * wv.x;
        acc[i].y += xv * wv.y;
        acc[i].z += xv * wv.z;
        acc[i].w += xv * wv.w;
      }
    }
    __syncthreads();
  }

#pragma unroll
  for (int i = 0; i < 4; ++i) {
    reinterpret_cast<float4*>(h + (size_t)(row0 + ty * 4 + i) * OUT_CH)[tx] =
        acc[i];
  }
}

// ---------------- Histogram of edge_row into offs (counts) ------------------
__global__ __launch_bounds__(256) void hist_kernel(
    const int* __restrict__ erow, int* __restrict__ offs) {
  for (int e = blockIdx.x * blockDim.x + threadIdx.x; e < N_EDGES;
       e += gridDim.x * blockDim.x) {
    atomicAdd(&offs[erow[e]], 1);
  }
}

// ---------------- Single-block exclusive scan (in-place) --------------------
#define SCAN_T 1024
__global__ __launch_bounds__(SCAN_T) void scan_kernel(int* __restrict__ offs) {
  __shared__ int part[SCAN_T];
  const int t = threadIdx.x;
  const int CH = (N_NODES + SCAN_T - 1) / SCAN_T;  // 98
  const int base = t * CH;

  int s = 0;
  for (int i = 0; i < CH; ++i) {
    int idx = base + i;
    if (idx < N_NODES) s += offs[idx];
  }
  part[t] = s;
  __syncthreads();
  for (int d = 1; d < SCAN_T; d <<= 1) {
    int v = (t >= d) ? part[t - d] : 0;
    __syncthreads();
    part[t] += v;
    __syncthreads();
  }
  int run = (t == 0) ? 0 : part[t - 1];
  for (int i = 0; i < CH; ++i) {
    int idx = base + i;
    if (idx < N_NODES) {
      int c = offs[idx];
      offs[idx] = run;
      run += c;
    }
  }
}

// ---------------- Placement: sorted (col,val) by row -------------------------
// After this kernel, offs[r] == end of row r (original offs[r+1]); row start
// is offs[r-1] (0 for r==0).
__global__ __launch_bounds__(256) void place_kernel(
    const int* __restrict__ erow, const int* __restrict__ ecol,
    const float* __restrict__ eval, int* __restrict__ offs,
    int* __restrict__ scol, float* __restrict__ sval) {
  for (int e = blockIdx.x * blockDim.x + threadIdx.x; e < N_EDGES;
       e += gridDim.x * blockDim.x) {
    int r = erow[e];
    int pos = atomicAdd(&offs[r], 1);
    scol[pos] = ecol[e];
    sval[pos] = eval[e];
  }
}

// ---------------- Aggregate: one wave per row --------------------------------
__global__ __launch_bounds__(256) void aggregate_kernel(
    const float* __restrict__ h, const int* __restrict__ offs,
    const int* __restrict__ scol, const float* __restrict__ sval,
    float* __restrict__ out) {
  const int wid = (int)((blockIdx.x * 256 + threadIdx.x) >> 6);  // row id
  const int lane = threadIdx.x & 63;
  if (wid >= N_NODES) return;

  const int start = (wid == 0) ? 0 : offs[wid - 1];
  const int end = offs[wid];
  const float2* __restrict__ h2 = reinterpret_cast<const float2*>(h);

  float2 acc = make_float2(0.f, 0.f);
  int e = start;
  // 2x unrolled for load ILP
  for (; e + 1 < end; e += 2) {
    int c0 = scol[e], c1 = scol[e + 1];
    float v0 = sval[e], v1 = sval[e + 1];
    float2 g0 = h2[(size_t)c0 * 64 + lane];
    float2 g1 = h2[(size_t)c1 * 64 + lane];
    acc.x += v0 * g0.x + v1 * g1.x;
    acc.y += v0 * g0.y + v1 * g1.y;
  }
  if (e < end) {
    int c = scol[e];
    float v = sval[e];
    float2 g = h2[(size_t)c * 64 + lane];
    acc.x += v * g.x;
    acc.y += v * g.y;
  }
  reinterpret_cast<float2*>(out)[(size_t)wid * 64 + lane] = acc;
}

extern "C" void kernel_launch(void* const* d_in, const int* in_sizes, int n_in,
                              void* d_out, int out_size, void* d_ws,
                              size_t ws_size, hipStream_t stream) {
  const float* x    = (const float*)d_in[0];
  const float* W    = (const float*)d_in[1];
  const float* b    = (const float*)d_in[2];
  const int* erow   = (const int*)d_in[3];
  const int* ecol   = (const int*)d_in[4];
  const float* eval = (const float*)d_in[5];
  float* out = (float*)d_out;

  // Workspace layout (needs ~77.2 MB):
  //   h:    [0, 51.2MB)                 N_NODES*OUT_CH floats
  //   offs: [51.2MB, +400KB)            N_NODES ints
  //   scol: [51.6MB, +12.8MB)           N_EDGES ints
  //   sval: [64.4MB, +12.8MB)           N_EDGES floats
  char* wsb = (char*)d_ws;
  float* h   = (float*)(wsb);
  int* offs  = (int*)(wsb + (size_t)N_NODES * OUT_CH * 4);
  int* scol  = (int*)(wsb + (size_t)N_NODES * OUT_CH * 4 + 400000);
  float* sval = (float*)(wsb + (size_t)N_NODES * OUT_CH * 4 + 400000 +
                         (size_t)N_EDGES * 4);

  // 1) h = x @ W + b
  gemm_bias_kernel<<<N_NODES / TM, 256, 0, stream>>>(x, W, b, h);

  // 2) counting sort by row -> CSR
  hipMemsetAsync(offs, 0, (size_t)N_NODES * 4, stream);
  hist_kernel<<<2048, 256, 0, stream>>>(erow, offs);
  scan_kernel<<<1, SCAN_T, 0, stream>>>(offs);
  place_kernel<<<2048, 256, 0, stream>>>(erow, ecol, eval, offs, scol, sval);

  // 3) aggregate: one wave per row, writes every output row (no memset needed)
  const int waves = N_NODES;
  const int blocks = (waves * 64 + 255) / 256;
  aggregate_kernel<<<blocks, 256, 0, stream>>>(h, offs, scol, sval, out);
}

// Round 4
// 707.556 us; speedup vs baseline: 7.6841x; 1.2053x over previous
//
#include <hip/hip_runtime.h>
#include <hip/hip_bf16.h>

#define N_NODES 100000
#define N_EDGES 3200000
#define IN_CH   256
#define OUT_CH  128

typedef int   iv4 __attribute__((ext_vector_type(4)));
typedef float fv4 __attribute__((ext_vector_type(4)));

// ---------------- GEMM: h = x @ W + b  ([N,256] @ [256,128]) ----------------
#define TM 32
#define KC 64

__global__ __launch_bounds__(256) void gemm_bias_kernel(
    const float* __restrict__ x, const float* __restrict__ W,
    const float* __restrict__ b, float* __restrict__ h) {
  __shared__ float xs[TM][KC];       // 8 KB
  __shared__ float ws[KC][OUT_CH];   // 32 KB

  const int tid = threadIdx.x;
  const int row0 = blockIdx.x * TM;
  const int tx = tid & 31;   // cols tx*4 .. tx*4+3
  const int ty = tid >> 5;   // rows ty*4 .. ty*4+3

  float4 acc[4];
  const float4 bias = reinterpret_cast<const float4*>(b)[tx];
#pragma unroll
  for (int i = 0; i < 4; ++i) acc[i] = bias;

  for (int kk = 0; kk < IN_CH; kk += KC) {
#pragma unroll
    for (int f = tid; f < TM * KC / 4; f += 256) {
      int r = f >> 4, kq = f & 15;
      float4 v = reinterpret_cast<const float4*>(
          x + (size_t)(row0 + r) * IN_CH + kk)[kq];
      reinterpret_cast<float4*>(&xs[r][0])[kq] = v;
    }
#pragma unroll
    for (int f = tid; f < KC * OUT_CH / 4; f += 256) {
      int k = f >> 5, nq = f & 31;
      float4 v = reinterpret_cast<const float4*>(
          W + (size_t)(kk + k) * OUT_CH)[nq];
      reinterpret_cast<float4*>(&ws[k][0])[nq] = v;
    }
    __syncthreads();

#pragma unroll 8
    for (int k = 0; k < KC; ++k) {
      float4 wv = reinterpret_cast<float4*>(&ws[k][0])[tx];
#pragma unroll
      for (int i = 0; i < 4; ++i) {
        float xv = xs[ty * 4 + i][k];
        acc[i].x += xv * wv.x;
        acc[i].y += xv * wv.y;
        acc[i].z += xv * wv.z;
        acc[i].w += xv * wv.w;
      }
    }
    __syncthreads();
  }

#pragma unroll
  for (int i = 0; i < 4; ++i) {
    reinterpret_cast<float4*>(h + (size_t)(row0 + ty * 4 + i) * OUT_CH)[tx] =
        acc[i];
  }
}

// ---------------- Histogram of edge_row into offs (counts) ------------------
// int4-vectorized; N_EDGES/4 = 800000 threads exactly (3125 blocks x 256).
__global__ __launch_bounds__(256) void hist_kernel(
    const int* __restrict__ erow, int* __restrict__ offs) {
  const int t = blockIdx.x * blockDim.x + threadIdx.x;
  iv4 r4 = __builtin_nontemporal_load(reinterpret_cast<const iv4*>(erow) + t);
  atomicAdd(&offs[r4.x], 1);
  atomicAdd(&offs[r4.y], 1);
  atomicAdd(&offs[r4.z], 1);
  atomicAdd(&offs[r4.w], 1);
}

// ---------------- 3-phase exclusive scan of offs[N_NODES] -------------------
#define SCAN_BLOCKS 391  // ceil(100000/256)

__global__ __launch_bounds__(256) void scan_partial(
    const int* __restrict__ offs, int* __restrict__ bsum) {
  __shared__ int s[256];
  const int t = threadIdx.x;
  const int idx = blockIdx.x * 256 + t;
  s[t] = (idx < N_NODES) ? offs[idx] : 0;
  __syncthreads();
#pragma unroll
  for (int d = 128; d > 0; d >>= 1) {
    if (t < d) s[t] += s[t + d];
    __syncthreads();
  }
  if (t == 0) bsum[blockIdx.x] = s[0];
}

__global__ __launch_bounds__(512) void scan_bsums(int* __restrict__ bsum) {
  __shared__ int s[512];
  const int t = threadIdx.x;
  const int v = (t < SCAN_BLOCKS) ? bsum[t] : 0;
  s[t] = v;
  __syncthreads();
  for (int d = 1; d < 512; d <<= 1) {
    int u = (t >= d) ? s[t - d] : 0;
    __syncthreads();
    s[t] += u;
    __syncthreads();
  }
  if (t < SCAN_BLOCKS) bsum[t] = s[t] - v;  // exclusive
}

__global__ __launch_bounds__(256) void scan_apply(
    int* __restrict__ offs, const int* __restrict__ bsum) {
  __shared__ int s[256];
  const int t = threadIdx.x;
  const int idx = blockIdx.x * 256 + t;
  const int v = (idx < N_NODES) ? offs[idx] : 0;
  s[t] = v;
  __syncthreads();
  for (int d = 1; d < 256; d <<= 1) {
    int u = (t >= d) ? s[t - d] : 0;
    __syncthreads();
    s[t] += u;
    __syncthreads();
  }
  if (idx < N_NODES) offs[idx] = s[t] - v + bsum[blockIdx.x];  // exclusive
}

// ---------------- Placement: packed (col,val) sorted by row ------------------
// After this kernel, offs[r] == end of row r; row start is offs[r-1].
__global__ __launch_bounds__(256) void place_kernel(
    const int* __restrict__ erow, const int* __restrict__ ecol,
    const float* __restrict__ eval, int* __restrict__ offs,
    long long* __restrict__ epk) {
  const int t = blockIdx.x * blockDim.x + threadIdx.x;
  iv4 r4 = __builtin_nontemporal_load(reinterpret_cast<const iv4*>(erow) + t);
  iv4 c4 = __builtin_nontemporal_load(reinterpret_cast<const iv4*>(ecol) + t);
  fv4 v4 = __builtin_nontemporal_load(reinterpret_cast<const fv4*>(eval) + t);

  int p0 = atomicAdd(&offs[r4.x], 1);
  int p1 = atomicAdd(&offs[r4.y], 1);
  int p2 = atomicAdd(&offs[r4.z], 1);
  int p3 = atomicAdd(&offs[r4.w], 1);

  long long k0 = ((long long)__float_as_int(v4.x) << 32) | (unsigned)c4.x;
  long long k1 = ((long long)__float_as_int(v4.y) << 32) | (unsigned)c4.y;
  long long k2 = ((long long)__float_as_int(v4.z) << 32) | (unsigned)c4.z;
  long long k3 = ((long long)__float_as_int(v4.w) << 32) | (unsigned)c4.w;
  __builtin_nontemporal_store(k0, epk + p0);
  __builtin_nontemporal_store(k1, epk + p1);
  __builtin_nontemporal_store(k2, epk + p2);
  __builtin_nontemporal_store(k3, epk + p3);
}

// ---------------- Aggregate: one wave per row --------------------------------
__global__ __launch_bounds__(256) void aggregate_kernel(
    const float* __restrict__ h, const int* __restrict__ offs,
    const long long* __restrict__ epk, float* __restrict__ out) {
  const int wid = (int)((blockIdx.x * 256 + threadIdx.x) >> 6);  // row id
  const int lane = threadIdx.x & 63;
  if (wid >= N_NODES) return;

  const int start = (wid == 0) ? 0 : offs[wid - 1];
  const int end = offs[wid];
  const float2* __restrict__ h2 = reinterpret_cast<const float2*>(h);

  float2 acc = make_float2(0.f, 0.f);
  int e = start;
  for (; e + 3 < end; e += 4) {
    long long q0 = epk[e + 0], q1 = epk[e + 1];
    long long q2 = epk[e + 2], q3 = epk[e + 3];
    float2 g0 = h2[(size_t)(int)q0 * 64 + lane];
    float2 g1 = h2[(size_t)(int)q1 * 64 + lane];
    float2 g2 = h2[(size_t)(int)q2 * 64 + lane];
    float2 g3 = h2[(size_t)(int)q3 * 64 + lane];
    float v0 = __int_as_float((int)(q0 >> 32));
    float v1 = __int_as_float((int)(q1 >> 32));
    float v2 = __int_as_float((int)(q2 >> 32));
    float v3 = __int_as_float((int)(q3 >> 32));
    acc.x += v0 * g0.x + v1 * g1.x + v2 * g2.x + v3 * g3.x;
    acc.y += v0 * g0.y + v1 * g1.y + v2 * g2.y + v3 * g3.y;
  }
  for (; e < end; ++e) {
    long long q = epk[e];
    float2 g = h2[(size_t)(int)q * 64 + lane];
    float v = __int_as_float((int)(q >> 32));
    acc.x += v * g.x;
    acc.y += v * g.y;
  }
  reinterpret_cast<float2*>(out)[(size_t)wid * 64 + lane] = acc;
}

extern "C" void kernel_launch(void* const* d_in, const int* in_sizes, int n_in,
                              void* d_out, int out_size, void* d_ws,
                              size_t ws_size, hipStream_t stream) {
  const float* x    = (const float*)d_in[0];
  const float* W    = (const float*)d_in[1];
  const float* b    = (const float*)d_in[2];
  const int* erow   = (const int*)d_in[3];
  const int* ecol   = (const int*)d_in[4];
  const float* eval = (const float*)d_in[5];
  float* out = (float*)d_out;

  // Workspace layout (~77.2 MB):
  //   h:    [0, 51.2MB)            N_NODES*OUT_CH floats
  //   offs: [+400KB)               N_NODES ints
  //   epk:  [+25.6MB)              N_EDGES packed (val<<32|col)
  //   bsum: [+1.6KB)               SCAN_BLOCKS ints
  char* wsb = (char*)d_ws;
  float* h        = (float*)(wsb);
  int* offs       = (int*)(wsb + (size_t)N_NODES * OUT_CH * 4);
  long long* epk  = (long long*)(wsb + (size_t)N_NODES * OUT_CH * 4 + 400000);
  int* bsum       = (int*)(wsb + (size_t)N_NODES * OUT_CH * 4 + 400000 +
                           (size_t)N_EDGES * 8);

  // 1) h = x @ W + b
  gemm_bias_kernel<<<N_NODES / TM, 256, 0, stream>>>(x, W, b, h);

  // 2) counting sort by row -> CSR (packed payload)
  (void)hipMemsetAsync(offs, 0, (size_t)N_NODES * 4, stream);
  hist_kernel<<<N_EDGES / 4 / 256, 256, 0, stream>>>(erow, offs);
  scan_partial<<<SCAN_BLOCKS, 256, 0, stream>>>(offs, bsum);
  scan_bsums<<<1, 512, 0, stream>>>(bsum);
  scan_apply<<<SCAN_BLOCKS, 256, 0, stream>>>(offs, bsum);
  place_kernel<<<N_EDGES / 4 / 256, 256, 0, stream>>>(erow, ecol, eval, offs,
                                                      epk);

  // 3) aggregate: one wave per row (writes every row; no out memset needed)
  const int blocks = (N_NODES * 64 + 255) / 256;
  aggregate_kernel<<<blocks, 256, 0, stream>>>(h, offs, epk, out);
}

// Round 5
// 508.637 us; speedup vs baseline: 10.6892x; 1.3911x over previous
//
#include <hip/hip_runtime.h>
#include <hip/hip_bf16.h>

#define N_NODES 100000
#define N_EDGES 3200000
#define IN_CH   256
#define OUT_CH  128

#define SLICES 8
#define ROWS_PER_SLICE (N_NODES / SLICES)  // 12500

typedef int   iv4 __attribute__((ext_vector_type(4)));
typedef float fv4 __attribute__((ext_vector_type(4)));

// round-to-nearest-even f32 -> bf16 (as u16 in low bits)
__device__ __forceinline__ unsigned bfr(float f) {
  unsigned u = __float_as_uint(f);
  return (u + 0x7FFFu + ((u >> 16) & 1u)) >> 16;
}

// ---------------- GEMM: h(bf16) = x @ W + b  ([N,256] @ [256,128]) ----------
#define TM 32
#define KC 64

__global__ __launch_bounds__(256) void gemm_bias_kernel(
    const float* __restrict__ x, const float* __restrict__ W,
    const float* __restrict__ b, unsigned short* __restrict__ hb) {
  __shared__ float xs[TM][KC];       // 8 KB
  __shared__ float ws[KC][OUT_CH];   // 32 KB

  const int tid = threadIdx.x;
  const int row0 = blockIdx.x * TM;
  const int tx = tid & 31;   // cols tx*4 .. tx*4+3
  const int ty = tid >> 5;   // rows ty*4 .. ty*4+3

  float4 acc[4];
  const float4 bias = reinterpret_cast<const float4*>(b)[tx];
#pragma unroll
  for (int i = 0; i < 4; ++i) acc[i] = bias;

  for (int kk = 0; kk < IN_CH; kk += KC) {
#pragma unroll
    for (int f = tid; f < TM * KC / 4; f += 256) {
      int r = f >> 4, kq = f & 15;
      float4 v = reinterpret_cast<const float4*>(
          x + (size_t)(row0 + r) * IN_CH + kk)[kq];
      reinterpret_cast<float4*>(&xs[r][0])[kq] = v;
    }
#pragma unroll
    for (int f = tid; f < KC * OUT_CH / 4; f += 256) {
      int k = f >> 5, nq = f & 31;
      float4 v = reinterpret_cast<const float4*>(
          W + (size_t)(kk + k) * OUT_CH)[nq];
      reinterpret_cast<float4*>(&ws[k][0])[nq] = v;
    }
    __syncthreads();

#pragma unroll 8
    for (int k = 0; k < KC; ++k) {
      float4 wv = reinterpret_cast<float4*>(&ws[k][0])[tx];
#pragma unroll
      for (int i = 0; i < 4; ++i) {
        float xv = xs[ty * 4 + i][k];
        acc[i].x += xv * wv.x;
        acc[i].y += xv * wv.y;
        acc[i].z += xv * wv.z;
        acc[i].w += xv * wv.w;
      }
    }
    __syncthreads();
  }

#pragma unroll
  for (int i = 0; i < 4; ++i) {
    uint2 pk;
    pk.x = bfr(acc[i].x) | (bfr(acc[i].y) << 16);
    pk.y = bfr(acc[i].z) | (bfr(acc[i].w) << 16);
    reinterpret_cast<uint2*>(hb + (size_t)(row0 + ty * 4 + i) * OUT_CH)[tx] =
        pk;
  }
}

// ---------------- Histogram of edge_row into offs (counts) ------------------
__global__ __launch_bounds__(256) void hist_kernel(
    const int* __restrict__ erow, int* __restrict__ offs) {
  const int t = blockIdx.x * blockDim.x + threadIdx.x;
  iv4 r4 = reinterpret_cast<const iv4*>(erow)[t];
  atomicAdd(&offs[r4.x], 1);
  atomicAdd(&offs[r4.y], 1);
  atomicAdd(&offs[r4.z], 1);
  atomicAdd(&offs[r4.w], 1);
}

// ---------------- 3-phase exclusive scan of offs[N_NODES] -------------------
#define SCAN_BLOCKS 391  // ceil(100000/256)

__global__ __launch_bounds__(256) void scan_partial(
    const int* __restrict__ offs, int* __restrict__ bsum) {
  __shared__ int s[256];
  const int t = threadIdx.x;
  const int idx = blockIdx.x * 256 + t;
  s[t] = (idx < N_NODES) ? offs[idx] : 0;
  __syncthreads();
#pragma unroll
  for (int d = 128; d > 0; d >>= 1) {
    if (t < d) s[t] += s[t + d];
    __syncthreads();
  }
  if (t == 0) bsum[blockIdx.x] = s[0];
}

__global__ __launch_bounds__(512) void scan_bsums(int* __restrict__ bsum) {
  __shared__ int s[512];
  const int t = threadIdx.x;
  const int v = (t < SCAN_BLOCKS) ? bsum[t] : 0;
  s[t] = v;
  __syncthreads();
  for (int d = 1; d < 512; d <<= 1) {
    int u = (t >= d) ? s[t - d] : 0;
    __syncthreads();
    s[t] += u;
    __syncthreads();
  }
  if (t < SCAN_BLOCKS) bsum[t] = s[t] - v;  // exclusive
}

__global__ __launch_bounds__(256) void scan_apply(
    int* __restrict__ offs, const int* __restrict__ bsum) {
  __shared__ int s[256];
  const int t = threadIdx.x;
  const int idx = blockIdx.x * 256 + t;
  const int v = (idx < N_NODES) ? offs[idx] : 0;
  s[t] = v;
  __syncthreads();
  for (int d = 1; d < 256; d <<= 1) {
    int u = (t >= d) ? s[t - d] : 0;
    __syncthreads();
    s[t] += u;
    __syncthreads();
  }
  if (idx < N_NODES) offs[idx] = s[t] - v + bsum[blockIdx.x];  // exclusive
}

// ---------------- Placement: packed (col,val) sorted by row, XCD-sliced ------
// Block b handles edge-chunk (b>>3) for row-slice (b&7). Under round-robin
// blockIdx->XCD mapping each XCD writes only its own 3.2MB epk slice, which
// stays L2-resident -> clean full-line writebacks instead of 8x partial ones.
// After this kernel, offs[r] == end of row r; row start is offs[r-1].
__global__ __launch_bounds__(256) void place_kernel(
    const int* __restrict__ erow, const int* __restrict__ ecol,
    const float* __restrict__ eval, int* __restrict__ offs,
    long long* __restrict__ epk) {
  const int slice = blockIdx.x & 7;
  const int chunk = blockIdx.x >> 3;
  const int t = chunk * 256 + threadIdx.x;
  const int lo = slice * ROWS_PER_SLICE;

  iv4 r4 = reinterpret_cast<const iv4*>(erow)[t];
  iv4 c4 = reinterpret_cast<const iv4*>(ecol)[t];
  fv4 v4 = reinterpret_cast<const fv4*>(eval)[t];

#pragma unroll
  for (int j = 0; j < 4; ++j) {
    int r = r4[j];
    if ((unsigned)(r - lo) < (unsigned)ROWS_PER_SLICE) {
      int pos = atomicAdd(&offs[r], 1);
      long long k =
          ((long long)__float_as_int(v4[j]) << 32) | (unsigned)c4[j];
      epk[pos] = k;
    }
  }
}

// ---------------- Aggregate: one wave per row --------------------------------
// lane owns channels {2*lane, 2*lane+1}; h is bf16 -> one u32 gather per edge.
__global__ __launch_bounds__(256) void aggregate_kernel(
    const unsigned short* __restrict__ hb, const int* __restrict__ offs,
    const long long* __restrict__ epk, float* __restrict__ out) {
  const int wid = (int)((blockIdx.x * 256 + threadIdx.x) >> 6);  // row id
  const int lane = threadIdx.x & 63;
  if (wid >= N_NODES) return;

  const int start = (wid == 0) ? 0 : offs[wid - 1];
  const int end = offs[wid];
  const unsigned* __restrict__ h32 = reinterpret_cast<const unsigned*>(hb);

  float2 acc = make_float2(0.f, 0.f);
  int e = start;
  for (; e + 3 < end; e += 4) {
    long long q0 = epk[e + 0], q1 = epk[e + 1];
    long long q2 = epk[e + 2], q3 = epk[e + 3];
    unsigned u0 = h32[(size_t)(int)q0 * 64 + lane];
    unsigned u1 = h32[(size_t)(int)q1 * 64 + lane];
    unsigned u2 = h32[(size_t)(int)q2 * 64 + lane];
    unsigned u3 = h32[(size_t)(int)q3 * 64 + lane];
    float v0 = __int_as_float((int)(q0 >> 32));
    float v1 = __int_as_float((int)(q1 >> 32));
    float v2 = __int_as_float((int)(q2 >> 32));
    float v3 = __int_as_float((int)(q3 >> 32));
    acc.x += v0 * __uint_as_float(u0 << 16) +
             v1 * __uint_as_float(u1 << 16) +
             v2 * __uint_as_float(u2 << 16) +
             v3 * __uint_as_float(u3 << 16);
    acc.y += v0 * __uint_as_float(u0 & 0xFFFF0000u) +
             v1 * __uint_as_float(u1 & 0xFFFF0000u) +
             v2 * __uint_as_float(u2 & 0xFFFF0000u) +
             v3 * __uint_as_float(u3 & 0xFFFF0000u);
  }
  for (; e < end; ++e) {
    long long q = epk[e];
    unsigned u = h32[(size_t)(int)q * 64 + lane];
    float v = __int_as_float((int)(q >> 32));
    acc.x += v * __uint_as_float(u << 16);
    acc.y += v * __uint_as_float(u & 0xFFFF0000u);
  }
  reinterpret_cast<float2*>(out)[(size_t)wid * 64 + lane] = acc;
}

extern "C" void kernel_launch(void* const* d_in, const int* in_sizes, int n_in,
                              void* d_out, int out_size, void* d_ws,
                              size_t ws_size, hipStream_t stream) {
  const float* x    = (const float*)d_in[0];
  const float* W    = (const float*)d_in[1];
  const float* b    = (const float*)d_in[2];
  const int* erow   = (const int*)d_in[3];
  const int* ecol   = (const int*)d_in[4];
  const float* eval = (const float*)d_in[5];
  float* out = (float*)d_out;

  // Workspace layout (~52 MB):
  //   hb:   [0, 25.6MB)            N_NODES*OUT_CH bf16
  //   offs: [+400KB)               N_NODES ints
  //   epk:  [+25.6MB)              N_EDGES packed (val<<32|col)
  //   bsum: [+1.6KB)               SCAN_BLOCKS ints
  char* wsb = (char*)d_ws;
  unsigned short* hb = (unsigned short*)(wsb);
  int* offs      = (int*)(wsb + (size_t)N_NODES * OUT_CH * 2);
  long long* epk = (long long*)(wsb + (size_t)N_NODES * OUT_CH * 2 + 400000);
  int* bsum      = (int*)(wsb + (size_t)N_NODES * OUT_CH * 2 + 400000 +
                          (size_t)N_EDGES * 8);

  // 1) h = x @ W + b  (stored bf16)
  gemm_bias_kernel<<<N_NODES / TM, 256, 0, stream>>>(x, W, b, hb);

  // 2) counting sort by row -> CSR (packed payload)
  (void)hipMemsetAsync(offs, 0, (size_t)N_NODES * 4, stream);
  hist_kernel<<<N_EDGES / 4 / 256, 256, 0, stream>>>(erow, offs);
  scan_partial<<<SCAN_BLOCKS, 256, 0, stream>>>(offs, bsum);
  scan_bsums<<<1, 512, 0, stream>>>(bsum);
  scan_apply<<<SCAN_BLOCKS, 256, 0, stream>>>(offs, bsum);
  place_kernel<<<(N_EDGES / 4 / 256) * SLICES, 256, 0, stream>>>(
      erow, ecol, eval, offs, epk);

  // 3) aggregate: one wave per row (writes every row; no out memset needed)
  const int blocks = (N_NODES * 64 + 255) / 256;
  aggregate_kernel<<<blocks, 256, 0, stream>>>(hb, offs, epk, out);
}

// Round 6
// 443.463 us; speedup vs baseline: 12.2602x; 1.1470x over previous
//
#include <hip/hip_runtime.h>
#include <hip/hip_bf16.h>

#define N_NODES 100000
#define N_EDGES 3200000
#define IN_CH   256
#define OUT_CH  128

#define SLICES 8
#define ROWS_PER_SLICE (N_NODES / SLICES)  // 12500

typedef int   iv4 __attribute__((ext_vector_type(4)));
typedef float fv4 __attribute__((ext_vector_type(4)));
typedef short bf16x8 __attribute__((ext_vector_type(8)));
typedef float f32x4 __attribute__((ext_vector_type(4)));
typedef unsigned short ushort_t;

// round-to-nearest-even f32 -> bf16 (as u16 in low bits)
__device__ __forceinline__ unsigned bfr(float f) {
  unsigned u = __float_as_uint(f);
  return (u + 0x7FFFu + ((u >> 16) & 1u)) >> 16;
}

// ---------------- W prep: wt[col][k] bf16 <- W[k][col] fp32 ------------------
__global__ __launch_bounds__(256) void wt_prep_kernel(
    const float* __restrict__ W, ushort_t* __restrict__ wt) {
  const int T = blockIdx.x * 256 + threadIdx.x;  // 0..8191
  const int col = T >> 6;
  const int k0 = (T & 63) * 4;
  uint2 pk;
  pk.x = bfr(W[(size_t)(k0 + 0) * OUT_CH + col]) |
         (bfr(W[(size_t)(k0 + 1) * OUT_CH + col]) << 16);
  pk.y = bfr(W[(size_t)(k0 + 2) * OUT_CH + col]) |
         (bfr(W[(size_t)(k0 + 3) * OUT_CH + col]) << 16);
  *reinterpret_cast<uint2*>(wt + (size_t)col * IN_CH + k0) = pk;
}

// ---------------- GEMM (MFMA bf16): hb = bf16(x @ W + b) ---------------------
// Block: 256 thr = 4 waves, 32 rows x 128 cols. Wave w: rowtile (w&1),
// col-half (w>>1). LDS [dim][k] bf16, XOR-swizzled byte^=(row&7)<<4.
#define GR 32

__global__ __launch_bounds__(256) void gemm_mfma_kernel(
    const float* __restrict__ x, const ushort_t* __restrict__ wt,
    const float* __restrict__ b, ushort_t* __restrict__ hb) {
  __shared__ alignas(16) char xs[GR * 512];    // 16 KB: [row][k]
  __shared__ alignas(16) char ws[128 * 512];   // 64 KB: [col][k]

  const int tid = threadIdx.x;
  const int row0 = blockIdx.x * GR;

  // stage x: 32 rows x 64 float4, coalesced; cvt to bf16 pairs
#pragma unroll
  for (int it = 0; it < 8; ++it) {
    int f = it * 256 + tid;
    int r = f >> 6, k4 = f & 63;
    fv4 v = *reinterpret_cast<const fv4*>(x + (size_t)(row0 + r) * IN_CH + k4 * 4);
    uint2 pk;
    pk.x = bfr(v.x) | (bfr(v.y) << 16);
    pk.y = bfr(v.z) | (bfr(v.w) << 16);
    unsigned off = (unsigned)(r * 512) + (((unsigned)(k4 * 8)) ^ ((unsigned)(r & 7) << 4));
    *reinterpret_cast<uint2*>(xs + off) = pk;
  }
  // stage wt: 128 cols x 32 16B-chunks, coalesced
#pragma unroll
  for (int it = 0; it < 16; ++it) {
    int f = it * 256 + tid;
    int col = f >> 5, ch = f & 31;
    bf16x8 v = *reinterpret_cast<const bf16x8*>(wt + (size_t)col * IN_CH + ch * 8);
    unsigned off = (unsigned)(col * 512) + (((unsigned)(ch * 16)) ^ ((unsigned)(col & 7) << 4));
    *reinterpret_cast<bf16x8*>(ws + off) = v;
  }
  __syncthreads();

  const int w = tid >> 6, l = tid & 63;
  const int lr = l & 15, lk = l >> 4;
  const int arow = (w & 1) * 16 + lr;   // x row within block tile
  const int cb = (w >> 1) * 64;         // col base for this wave

  // swapped-operand mfma: D[i=Wcol][j=xrow]; lane: xrow=lr, Wcols=cb+n*16+lk*4+reg
  f32x4 acc[4];
#pragma unroll
  for (int n = 0; n < 4; ++n) {
    int c0 = cb + n * 16 + lk * 4;
    acc[n] = (f32x4){b[c0], b[c0 + 1], b[c0 + 2], b[c0 + 3]};
  }

  const unsigned axm = (unsigned)(arow & 7) << 4;
#pragma unroll
  for (int kk = 0; kk < 8; ++kk) {
    bf16x8 af = *reinterpret_cast<const bf16x8*>(
        xs + (unsigned)(arow * 512) + (((unsigned)(kk * 64 + lk * 16)) ^ axm));
#pragma unroll
    for (int n = 0; n < 4; ++n) {
      int bcol = cb + n * 16 + lr;
      bf16x8 bf_ = *reinterpret_cast<const bf16x8*>(
          ws + (unsigned)(bcol * 512) +
          (((unsigned)(kk * 64 + lk * 16)) ^ ((unsigned)(bcol & 7) << 4)));
      acc[n] = __builtin_amdgcn_mfma_f32_16x16x32_bf16(bf_, af, acc[n], 0, 0, 0);
    }
  }

  const int grow = row0 + arow;
#pragma unroll
  for (int n = 0; n < 4; ++n) {
    int c0 = cb + n * 16 + lk * 4;
    uint2 pk;
    pk.x = bfr(acc[n][0]) | (bfr(acc[n][1]) << 16);
    pk.y = bfr(acc[n][2]) | (bfr(acc[n][3]) << 16);
    *reinterpret_cast<uint2*>(hb + (size_t)grow * OUT_CH + c0) = pk;
  }
}

// ---------------- Histogram of edge_row into offs (counts) ------------------
__global__ __launch_bounds__(256) void hist_kernel(
    const int* __restrict__ erow, int* __restrict__ offs) {
  const int t = blockIdx.x * blockDim.x + threadIdx.x;
  iv4 r4 = __builtin_nontemporal_load(reinterpret_cast<const iv4*>(erow) + t);
  atomicAdd(&offs[r4.x], 1);
  atomicAdd(&offs[r4.y], 1);
  atomicAdd(&offs[r4.z], 1);
  atomicAdd(&offs[r4.w], 1);
}

// ---------------- 3-phase exclusive scan of offs[N_NODES] -------------------
#define SCAN_BLOCKS 391  // ceil(100000/256)

__global__ __launch_bounds__(256) void scan_partial(
    const int* __restrict__ offs, int* __restrict__ bsum) {
  __shared__ int s[256];
  const int t = threadIdx.x;
  const int idx = blockIdx.x * 256 + t;
  s[t] = (idx < N_NODES) ? offs[idx] : 0;
  __syncthreads();
#pragma unroll
  for (int d = 128; d > 0; d >>= 1) {
    if (t < d) s[t] += s[t + d];
    __syncthreads();
  }
  if (t == 0) bsum[blockIdx.x] = s[0];
}

__global__ __launch_bounds__(512) void scan_bsums(int* __restrict__ bsum) {
  __shared__ int s[512];
  const int t = threadIdx.x;
  const int v = (t < SCAN_BLOCKS) ? bsum[t] : 0;
  s[t] = v;
  __syncthreads();
  for (int d = 1; d < 512; d <<= 1) {
    int u = (t >= d) ? s[t - d] : 0;
    __syncthreads();
    s[t] += u;
    __syncthreads();
  }
  if (t < SCAN_BLOCKS) bsum[t] = s[t] - v;  // exclusive
}

__global__ __launch_bounds__(256) void scan_apply(
    int* __restrict__ offs, const int* __restrict__ bsum) {
  __shared__ int s[256];
  const int t = threadIdx.x;
  const int idx = blockIdx.x * 256 + t;
  const int v = (idx < N_NODES) ? offs[idx] : 0;
  s[t] = v;
  __syncthreads();
  for (int d = 1; d < 256; d <<= 1) {
    int u = (t >= d) ? s[t - d] : 0;
    __syncthreads();
    s[t] += u;
    __syncthreads();
  }
  if (idx < N_NODES) offs[idx] = s[t] - v + bsum[blockIdx.x];  // exclusive
}

// ---------------- Placement: packed (col,val) sorted by row, XCD-sliced ------
// Block b: edge-chunk (b>>3) for row-slice (b&7). Nontemporal edge streams so
// the XCD's 3.2MB epk slice stays L2-resident (clean full-line writebacks).
__global__ __launch_bounds__(256) void place_kernel(
    const int* __restrict__ erow, const int* __restrict__ ecol,
    const float* __restrict__ eval, int* __restrict__ offs,
    long long* __restrict__ epk) {
  const int slice = blockIdx.x & 7;
  const int chunk = blockIdx.x >> 3;
  const int t = chunk * 256 + threadIdx.x;
  const int lo = slice * ROWS_PER_SLICE;

  iv4 r4 = __builtin_nontemporal_load(reinterpret_cast<const iv4*>(erow) + t);
  iv4 c4 = __builtin_nontemporal_load(reinterpret_cast<const iv4*>(ecol) + t);
  fv4 v4 = __builtin_nontemporal_load(reinterpret_cast<const fv4*>(eval) + t);

#pragma unroll
  for (int j = 0; j < 4; ++j) {
    int r = r4[j];
    if ((unsigned)(r - lo) < (unsigned)ROWS_PER_SLICE) {
      int pos = atomicAdd(&offs[r], 1);
      long long k =
          ((long long)__float_as_int(v4[j]) << 32) | (unsigned)c4[j];
      epk[pos] = k;
    }
  }
}

// ---------------- Aggregate: one wave per row --------------------------------
__global__ __launch_bounds__(256) void aggregate_kernel(
    const ushort_t* __restrict__ hb, const int* __restrict__ offs,
    const long long* __restrict__ epk, float* __restrict__ out) {
  const int wid = (int)((blockIdx.x * 256 + threadIdx.x) >> 6);  // row id
  const int lane = threadIdx.x & 63;
  if (wid >= N_NODES) return;

  const int start = (wid == 0) ? 0 : offs[wid - 1];
  const int end = offs[wid];
  const unsigned* __restrict__ h32 = reinterpret_cast<const unsigned*>(hb);

  float2 acc = make_float2(0.f, 0.f);
  int e = start;
  for (; e + 3 < end; e += 4) {
    long long q0 = epk[e + 0], q1 = epk[e + 1];
    long long q2 = epk[e + 2], q3 = epk[e + 3];
    unsigned u0 = h32[(size_t)(int)q0 * 64 + lane];
    unsigned u1 = h32[(size_t)(int)q1 * 64 + lane];
    unsigned u2 = h32[(size_t)(int)q2 * 64 + lane];
    unsigned u3 = h32[(size_t)(int)q3 * 64 + lane];
    float v0 = __int_as_float((int)(q0 >> 32));
    float v1 = __int_as_float((int)(q1 >> 32));
    float v2 = __int_as_float((int)(q2 >> 32));
    float v3 = __int_as_float((int)(q3 >> 32));
    acc.x += v0 * __uint_as_float(u0 << 16) +
             v1 * __uint_as_float(u1 << 16) +
             v2 * __uint_as_float(u2 << 16) +
             v3 * __uint_as_float(u3 << 16);
    acc.y += v0 * __uint_as_float(u0 & 0xFFFF0000u) +
             v1 * __uint_as_float(u1 & 0xFFFF0000u) +
             v2 * __uint_as_float(u2 & 0xFFFF0000u) +
             v3 * __uint_as_float(u3 & 0xFFFF0000u);
  }
  for (; e < end; ++e) {
    long long q = epk[e];
    unsigned u = h32[(size_t)(int)q * 64 + lane];
    float v = __int_as_float((int)(q >> 32));
    acc.x += v * __uint_as_float(u << 16);
    acc.y += v * __uint_as_float(u & 0xFFFF0000u);
  }
  reinterpret_cast<float2*>(out)[(size_t)wid * 64 + lane] = acc;
}

extern "C" void kernel_launch(void* const* d_in, const int* in_sizes, int n_in,
                              void* d_out, int out_size, void* d_ws,
                              size_t ws_size, hipStream_t stream) {
  const float* x    = (const float*)d_in[0];
  const float* W    = (const float*)d_in[1];
  const float* b    = (const float*)d_in[2];
  const int* erow   = (const int*)d_in[3];
  const int* ecol   = (const int*)d_in[4];
  const float* eval = (const float*)d_in[5];
  float* out = (float*)d_out;

  // Workspace layout (~51.7 MB):
  //   hb:   [0, 25.6MB)            N_NODES*OUT_CH bf16
  //   offs: [25.6MB, +400KB)       N_NODES ints
  //   epk:  [26.0MB, +25.6MB)      N_EDGES packed (val<<32|col)
  //   bsum: [51.6MB, +1.6KB)       SCAN_BLOCKS ints
  //   wt:   [+64KB]                W^T bf16 [128][256]
  char* wsb = (char*)d_ws;
  ushort_t* hb   = (ushort_t*)(wsb);
  int* offs      = (int*)(wsb + 25600000);
  long long* epk = (long long*)(wsb + 26000000);
  int* bsum      = (int*)(wsb + 51600000);
  ushort_t* wt   = (ushort_t*)(wsb + 51601600);

  // 1) h = x @ W + b  (bf16 MFMA; wt precomputed transposed bf16)
  wt_prep_kernel<<<32, 256, 0, stream>>>(W, wt);
  gemm_mfma_kernel<<<N_NODES / GR, 256, 0, stream>>>(x, wt, b, hb);

  // 2) counting sort by row -> CSR (packed payload)
  (void)hipMemsetAsync(offs, 0, (size_t)N_NODES * 4, stream);
  hist_kernel<<<N_EDGES / 4 / 256, 256, 0, stream>>>(erow, offs);
  scan_partial<<<SCAN_BLOCKS, 256, 0, stream>>>(offs, bsum);
  scan_bsums<<<1, 512, 0, stream>>>(bsum);
  scan_apply<<<SCAN_BLOCKS, 256, 0, stream>>>(offs, bsum);
  place_kernel<<<(N_EDGES / 4 / 256) * SLICES, 256, 0, stream>>>(
      erow, ecol, eval, offs, epk);

  // 3) aggregate: one wave per row (writes every row; no out memset needed)
  const int blocks = (N_NODES * 64 + 255) / 256;
  aggregate_kernel<<<blocks, 256, 0, stream>>>(hb, offs, epk, out);
}

// Round 7
// 428.793 us; speedup vs baseline: 12.6796x; 1.0342x over previous
//
#include <hip/hip_runtime.h>
#include <hip/hip_bf16.h>

#define N_NODES 100000
#define N_EDGES 3200000
#define IN_CH   256
#define OUT_CH  128

#define NBUCKET 782                 // bucket = row >> 7 (128 rows each)
#define RPB 128
#define NBLK 256                    // hist/scatter blocks
#define CHUNK (N_EDGES / NBLK)      // 12500 edges per block
#define CHUNK4 (CHUNK / 4)          // 3125 iv4 per block
#define CAP 5120                    // LDS edge capacity per bucket (+16 sigma)
#define QREG 20                     // ceil(CAP/256)

typedef int   iv4 __attribute__((ext_vector_type(4)));
typedef float fv4 __attribute__((ext_vector_type(4)));
typedef short bf16x8 __attribute__((ext_vector_type(8)));
typedef float f32x4 __attribute__((ext_vector_type(4)));
typedef unsigned long long u64;
typedef unsigned short ushort_t;

// round-to-nearest-even f32 -> bf16 (as u16 in low bits)
__device__ __forceinline__ unsigned bfr(float f) {
  unsigned u = __float_as_uint(f);
  return (u + 0x7FFFu + ((u >> 16) & 1u)) >> 16;
}

// ---------------- W prep: wt[col][k] bf16 <- W[k][col] fp32 ------------------
__global__ __launch_bounds__(256) void wt_prep_kernel(
    const float* __restrict__ W, ushort_t* __restrict__ wt) {
  const int T = blockIdx.x * 256 + threadIdx.x;  // 0..8191
  const int col = T >> 6;
  const int k0 = (T & 63) * 4;
  uint2 pk;
  pk.x = bfr(W[(size_t)(k0 + 0) * OUT_CH + col]) |
         (bfr(W[(size_t)(k0 + 1) * OUT_CH + col]) << 16);
  pk.y = bfr(W[(size_t)(k0 + 2) * OUT_CH + col]) |
         (bfr(W[(size_t)(k0 + 3) * OUT_CH + col]) << 16);
  *reinterpret_cast<uint2*>(wt + (size_t)col * IN_CH + k0) = pk;
}

// ---------------- GEMM (MFMA bf16): hb = bf16(x @ W + b) ---------------------
#define GR 32

__global__ __launch_bounds__(256) void gemm_mfma_kernel(
    const float* __restrict__ x, const ushort_t* __restrict__ wt,
    const float* __restrict__ b, ushort_t* __restrict__ hb) {
  __shared__ alignas(16) char xs[GR * 512];    // 16 KB: [row][k]
  __shared__ alignas(16) char ws[128 * 512];   // 64 KB: [col][k]

  const int tid = threadIdx.x;
  const int row0 = blockIdx.x * GR;

#pragma unroll
  for (int it = 0; it < 8; ++it) {
    int f = it * 256 + tid;
    int r = f >> 6, k4 = f & 63;
    fv4 v = *reinterpret_cast<const fv4*>(x + (size_t)(row0 + r) * IN_CH + k4 * 4);
    uint2 pk;
    pk.x = bfr(v.x) | (bfr(v.y) << 16);
    pk.y = bfr(v.z) | (bfr(v.w) << 16);
    unsigned off = (unsigned)(r * 512) + (((unsigned)(k4 * 8)) ^ ((unsigned)(r & 7) << 4));
    *reinterpret_cast<uint2*>(xs + off) = pk;
  }
#pragma unroll
  for (int it = 0; it < 16; ++it) {
    int f = it * 256 + tid;
    int col = f >> 5, ch = f & 31;
    bf16x8 v = *reinterpret_cast<const bf16x8*>(wt + (size_t)col * IN_CH + ch * 8);
    unsigned off = (unsigned)(col * 512) + (((unsigned)(ch * 16)) ^ ((unsigned)(col & 7) << 4));
    *reinterpret_cast<bf16x8*>(ws + off) = v;
  }
  __syncthreads();

  const int w = tid >> 6, l = tid & 63;
  const int lr = l & 15, lk = l >> 4;
  const int arow = (w & 1) * 16 + lr;
  const int cb = (w >> 1) * 64;

  f32x4 acc[4];
#pragma unroll
  for (int n = 0; n < 4; ++n) {
    int c0 = cb + n * 16 + lk * 4;
    acc[n] = (f32x4){b[c0], b[c0 + 1], b[c0 + 2], b[c0 + 3]};
  }

  const unsigned axm = (unsigned)(arow & 7) << 4;
#pragma unroll
  for (int kk = 0; kk < 8; ++kk) {
    bf16x8 af = *reinterpret_cast<const bf16x8*>(
        xs + (unsigned)(arow * 512) + (((unsigned)(kk * 64 + lk * 16)) ^ axm));
#pragma unroll
    for (int n = 0; n < 4; ++n) {
      int bcol = cb + n * 16 + lr;
      bf16x8 bf_ = *reinterpret_cast<const bf16x8*>(
          ws + (unsigned)(bcol * 512) +
          (((unsigned)(kk * 64 + lk * 16)) ^ ((unsigned)(bcol & 7) << 4)));
      acc[n] = __builtin_amdgcn_mfma_f32_16x16x32_bf16(bf_, af, acc[n], 0, 0, 0);
    }
  }

  const int grow = row0 + arow;
#pragma unroll
  for (int n = 0; n < 4; ++n) {
    int c0 = cb + n * 16 + lk * 4;
    uint2 pk;
    pk.x = bfr(acc[n][0]) | (bfr(acc[n][1]) << 16);
    pk.y = bfr(acc[n][2]) | (bfr(acc[n][3]) << 16);
    *reinterpret_cast<uint2*>(hb + (size_t)grow * OUT_CH + c0) = pk;
  }
}

// ---------------- histA: per-block bucket histogram (bucket-major out) -------
__global__ __launch_bounds__(256) void histA_kernel(
    const int* __restrict__ erow, int* __restrict__ histA) {
  __shared__ int hcnt[NBUCKET];
  const int blk = blockIdx.x, tid = threadIdx.x;
  for (int i = tid; i < NBUCKET; i += 256) hcnt[i] = 0;
  __syncthreads();
  const iv4* er4 = reinterpret_cast<const iv4*>(erow) + blk * CHUNK4;
  for (int i = tid; i < CHUNK4; i += 256) {
    iv4 r4 = __builtin_nontemporal_load(er4 + i);
    atomicAdd(&hcnt[r4.x >> 7], 1);
    atomicAdd(&hcnt[r4.y >> 7], 1);
    atomicAdd(&hcnt[r4.z >> 7], 1);
    atomicAdd(&hcnt[r4.w >> 7], 1);
  }
  __syncthreads();
  for (int b2 = tid; b2 < NBUCKET; b2 += 256) histA[b2 * NBLK + blk] = hcnt[b2];
}

// ---------------- 3-phase exclusive scan over NBUCKET*NBLK = 200192 ---------
__global__ __launch_bounds__(256) void scanA_partial(
    const int* __restrict__ a, int* __restrict__ bsum) {
  __shared__ int s[256];
  const int t = threadIdx.x;
  s[t] = a[blockIdx.x * 256 + t];
  __syncthreads();
#pragma unroll
  for (int d = 128; d > 0; d >>= 1) {
    if (t < d) s[t] += s[t + d];
    __syncthreads();
  }
  if (t == 0) bsum[blockIdx.x] = s[0];
}

__global__ __launch_bounds__(1024) void scanA_bsums(int* __restrict__ bsum) {
  __shared__ int s[1024];
  const int t = threadIdx.x;
  const int v = (t < NBUCKET) ? bsum[t] : 0;
  s[t] = v;
  __syncthreads();
  for (int d = 1; d < 1024; d <<= 1) {
    int u = (t >= d) ? s[t - d] : 0;
    __syncthreads();
    s[t] += u;
    __syncthreads();
  }
  if (t < NBUCKET) bsum[t] = s[t] - v;  // exclusive
}

__global__ __launch_bounds__(256) void scanA_apply(
    int* __restrict__ a, const int* __restrict__ bsum) {
  __shared__ int s[256];
  const int t = threadIdx.x;
  const int idx = blockIdx.x * 256 + t;
  const int v = a[idx];
  s[t] = v;
  __syncthreads();
  for (int d = 1; d < 256; d <<= 1) {
    int u = (t >= d) ? s[t - d] : 0;
    __syncthreads();
    s[t] += u;
    __syncthreads();
  }
  a[idx] = s[t] - v + bsum[blockIdx.x];  // exclusive
}

// ---------------- scatterA: partition edges into bucket-major tmp ------------
// Each (bucket, blk) segment is exclusively owned -> monotone write streams.
__global__ __launch_bounds__(256) void scatterA_kernel(
    const int* __restrict__ erow, const int* __restrict__ ecol,
    const float* __restrict__ eval, const int* __restrict__ scanA,
    u64* __restrict__ tmp) {
  __shared__ int cur[NBUCKET];
  const int blk = blockIdx.x, tid = threadIdx.x;
  for (int b2 = tid; b2 < NBUCKET; b2 += 256) cur[b2] = scanA[b2 * NBLK + blk];
  __syncthreads();
  const iv4* er4 = reinterpret_cast<const iv4*>(erow) + blk * CHUNK4;
  const iv4* ec4 = reinterpret_cast<const iv4*>(ecol) + blk * CHUNK4;
  const fv4* ev4 = reinterpret_cast<const fv4*>(eval) + blk * CHUNK4;
  for (int i = tid; i < CHUNK4; i += 256) {
    iv4 r4 = __builtin_nontemporal_load(er4 + i);
    iv4 c4 = __builtin_nontemporal_load(ec4 + i);
    fv4 v4 = __builtin_nontemporal_load(ev4 + i);
#pragma unroll
    for (int j = 0; j < 4; ++j) {
      int r = r4[j];
      int pos = atomicAdd(&cur[r >> 7], 1);
      u64 q = ((u64)(unsigned)__float_as_int(v4[j]) << 32) |
              ((unsigned)(r & 127) << 17) | (unsigned)c4[j];
      __builtin_nontemporal_store(q, tmp + pos);
    }
  }
}

// ---------------- bucket_agg: in-LDS row sort + aggregate + store ------------
__global__ __launch_bounds__(256) void bucket_agg_kernel(
    const ushort_t* __restrict__ hb, const u64* __restrict__ tmp,
    const int* __restrict__ scanA, float* __restrict__ out) {
  __shared__ u64 eds[CAP];            // 40 KB sorted edges
  __shared__ int rcnt[RPB];
  __shared__ int rstart[RPB + 1];
  __shared__ int rcur[RPB];
  __shared__ int sscan[RPB];

  const int bkt = blockIdx.x, tid = threadIdx.x;
  const int base = scanA[bkt * NBLK];
  const int end = (bkt == NBUCKET - 1) ? N_EDGES : scanA[(bkt + 1) * NBLK];
  const int cnt = end - base;
  const int row0 = bkt * RPB;
  const unsigned* __restrict__ h32 = reinterpret_cast<const unsigned*>(hb);
  const int w = tid >> 6, lane = tid & 63;

  if (cnt <= CAP) {
    if (tid < RPB) rcnt[tid] = 0;
    __syncthreads();

    u64 qreg[QREG];
#pragma unroll
    for (int j = 0; j < QREG; ++j) {
      int i = j * 256 + tid;
      if (i < cnt) {
        qreg[j] = __builtin_nontemporal_load(tmp + base + i);
        atomicAdd(&rcnt[(unsigned)(qreg[j] >> 17) & 127u], 1);
      }
    }
    __syncthreads();

    // exclusive scan of 128 row counts
    if (tid < RPB) sscan[tid] = rcnt[tid];
    __syncthreads();
    for (int d = 1; d < RPB; d <<= 1) {
      int v = (tid < RPB && tid >= d) ? sscan[tid - d] : 0;
      __syncthreads();
      if (tid < RPB) sscan[tid] += v;
      __syncthreads();
    }
    if (tid < RPB) { rstart[tid + 1] = sscan[tid]; }
    if (tid == 0) rstart[0] = 0;
    __syncthreads();
    if (tid < RPB) rcur[tid] = rstart[tid];
    __syncthreads();

#pragma unroll
    for (int j = 0; j < QREG; ++j) {
      int i = j * 256 + tid;
      if (i < cnt) {
        u64 q = qreg[j];
        int r = (unsigned)(q >> 17) & 127u;
        int pos = atomicAdd(&rcur[r], 1);
        eds[pos] = (q & 0xFFFFFFFF00000000ull) | (unsigned)(q & 0x1FFFFu);
      }
    }
    __syncthreads();

    // aggregate: wave w handles rows w, w+4, ... ; lane owns 2 channels
    for (int r = w; r < RPB; r += 4) {
      int grow = row0 + r;
      if (grow >= N_NODES) break;
      int e = rstart[r], e2 = rstart[r + 1];
      float ax = 0.f, ay = 0.f;
      for (; e + 3 < e2; e += 4) {
        u64 q0 = eds[e + 0], q1 = eds[e + 1];
        u64 q2 = eds[e + 2], q3 = eds[e + 3];
        unsigned u0 = h32[(size_t)(unsigned)(q0 & 0x1FFFFu) * 64 + lane];
        unsigned u1 = h32[(size_t)(unsigned)(q1 & 0x1FFFFu) * 64 + lane];
        unsigned u2 = h32[(size_t)(unsigned)(q2 & 0x1FFFFu) * 64 + lane];
        unsigned u3 = h32[(size_t)(unsigned)(q3 & 0x1FFFFu) * 64 + lane];
        float v0 = __int_as_float((int)(q0 >> 32));
        float v1 = __int_as_float((int)(q1 >> 32));
        float v2 = __int_as_float((int)(q2 >> 32));
        float v3 = __int_as_float((int)(q3 >> 32));
        ax += v0 * __uint_as_float(u0 << 16) + v1 * __uint_as_float(u1 << 16) +
              v2 * __uint_as_float(u2 << 16) + v3 * __uint_as_float(u3 << 16);
        ay += v0 * __uint_as_float(u0 & 0xFFFF0000u) +
              v1 * __uint_as_float(u1 & 0xFFFF0000u) +
              v2 * __uint_as_float(u2 & 0xFFFF0000u) +
              v3 * __uint_as_float(u3 & 0xFFFF0000u);
      }
      for (; e < e2; ++e) {
        u64 q = eds[e];
        unsigned u = h32[(size_t)(unsigned)(q & 0x1FFFFu) * 64 + lane];
        float v = __int_as_float((int)(q >> 32));
        ax += v * __uint_as_float(u << 16);
        ay += v * __uint_as_float(u & 0xFFFF0000u);
      }
      reinterpret_cast<float2*>(out)[(size_t)grow * 64 + lane] =
          make_float2(ax, ay);
    }
  } else {
    // fallback (statistically unreachable): zero rows then global atomics
    for (int i = tid; i < RPB * 64; i += 256) {
      int grow = row0 + (i >> 6);
      if (grow < N_NODES)
        reinterpret_cast<float2*>(out)[(size_t)grow * 64 + (i & 63)] =
            make_float2(0.f, 0.f);
    }
    __syncthreads();
    for (int i = w; i < cnt; i += 4) {
      u64 q = tmp[base + i];
      int r = (unsigned)(q >> 17) & 127u;
      unsigned col = (unsigned)(q & 0x1FFFFu);
      float v = __int_as_float((int)(q >> 32));
      unsigned u = h32[(size_t)col * 64 + lane];
      if (row0 + r < N_NODES) {
        atomicAdd(out + (size_t)(row0 + r) * OUT_CH + lane * 2,
                  v * __uint_as_float(u << 16));
        atomicAdd(out + (size_t)(row0 + r) * OUT_CH + lane * 2 + 1,
                  v * __uint_as_float(u & 0xFFFF0000u));
      }
    }
  }
}

extern "C" void kernel_launch(void* const* d_in, const int* in_sizes, int n_in,
                              void* d_out, int out_size, void* d_ws,
                              size_t ws_size, hipStream_t stream) {
  const float* x    = (const float*)d_in[0];
  const float* W    = (const float*)d_in[1];
  const float* b    = (const float*)d_in[2];
  const int* erow   = (const int*)d_in[3];
  const int* ecol   = (const int*)d_in[4];
  const float* eval = (const float*)d_in[5];
  float* out = (float*)d_out;

  // Workspace (~52.1 MB):
  //   hb:    [0, 25.6MB)          N_NODES*OUT_CH bf16
  //   tmp:   [25.6MB, +25.6MB)    N_EDGES u64 (bucket-partitioned edges)
  //   scanA: [51.2MB, +800768B)   NBUCKET*NBLK ints
  //   bsum:  [+3128B]             NBUCKET ints
  //   wt:    [+64KB]              W^T bf16 [128][256]
  char* wsb = (char*)d_ws;
  ushort_t* hb  = (ushort_t*)(wsb);
  u64* tmp      = (u64*)(wsb + 25600000);
  int* scanA    = (int*)(wsb + 51200000);
  int* bsum     = (int*)(wsb + 52000768);
  ushort_t* wt  = (ushort_t*)(wsb + 52003904);

  // 1) h = x @ W + b  (bf16 MFMA)
  wt_prep_kernel<<<32, 256, 0, stream>>>(W, wt);
  gemm_mfma_kernel<<<N_NODES / GR, 256, 0, stream>>>(x, wt, b, hb);

  // 2) bucket partition (782 buckets of 128 rows)
  histA_kernel<<<NBLK, 256, 0, stream>>>(erow, scanA);
  scanA_partial<<<NBUCKET, 256, 0, stream>>>(scanA, bsum);
  scanA_bsums<<<1, 1024, 0, stream>>>(bsum);
  scanA_apply<<<NBUCKET, 256, 0, stream>>>(scanA, bsum);
  scatterA_kernel<<<NBLK, 256, 0, stream>>>(erow, ecol, eval, scanA, tmp);

  // 3) fused in-LDS row-sort + aggregate + store
  bucket_agg_kernel<<<NBUCKET, 256, 0, stream>>>(hb, tmp, scanA, out);
}

// Round 8
// 291.020 us; speedup vs baseline: 18.6824x; 1.4734x over previous
//
#include <hip/hip_runtime.h>
#include <hip/hip_bf16.h>

#define N_NODES 100000
#define N_EDGES 3200000
#define IN_CH   256
#define OUT_CH  128

#define RPB 64                      // rows per bucket
#define NBUCKET 1563                // ceil(100000/64)
#define NBLK 256                    // hist/scatter blocks
#define CHUNK (N_EDGES / NBLK)      // 12500 edges per block
#define CHUNK4 (CHUNK / 4)          // 3125 iv4 per block
#define CAP 2816                    // LDS edge cap per bucket (mu+17sigma)
#define AGG_T 512                   // bucket_agg threads
#define QREG 6                      // ceil(CAP/AGG_T)

typedef int   iv4 __attribute__((ext_vector_type(4)));
typedef float fv4 __attribute__((ext_vector_type(4)));
typedef short bf16x8 __attribute__((ext_vector_type(8)));
typedef float f32x4 __attribute__((ext_vector_type(4)));
typedef unsigned long long u64;
typedef unsigned short ushort_t;

// round-to-nearest-even f32 -> bf16 (as u16 in low bits)
__device__ __forceinline__ unsigned bfr(float f) {
  unsigned u = __float_as_uint(f);
  return (u + 0x7FFFu + ((u >> 16) & 1u)) >> 16;
}

// ---------------- W prep: wt[col][k] bf16 <- W[k][col] fp32 ------------------
__global__ __launch_bounds__(256) void wt_prep_kernel(
    const float* __restrict__ W, ushort_t* __restrict__ wt) {
  const int T = blockIdx.x * 256 + threadIdx.x;  // 0..8191
  const int col = T >> 6;
  const int k0 = (T & 63) * 4;
  uint2 pk;
  pk.x = bfr(W[(size_t)(k0 + 0) * OUT_CH + col]) |
         (bfr(W[(size_t)(k0 + 1) * OUT_CH + col]) << 16);
  pk.y = bfr(W[(size_t)(k0 + 2) * OUT_CH + col]) |
         (bfr(W[(size_t)(k0 + 3) * OUT_CH + col]) << 16);
  *reinterpret_cast<uint2*>(wt + (size_t)col * IN_CH + k0) = pk;
}

// ---------------- GEMM (MFMA bf16): hb = bf16(x @ W + b) ---------------------
#define GR 32

__global__ __launch_bounds__(256) void gemm_mfma_kernel(
    const float* __restrict__ x, const ushort_t* __restrict__ wt,
    const float* __restrict__ b, ushort_t* __restrict__ hb) {
  __shared__ alignas(16) char xs[GR * 512];    // 16 KB: [row][k]
  __shared__ alignas(16) char ws[128 * 512];   // 64 KB: [col][k]

  const int tid = threadIdx.x;
  const int row0 = blockIdx.x * GR;

#pragma unroll
  for (int it = 0; it < 8; ++it) {
    int f = it * 256 + tid;
    int r = f >> 6, k4 = f & 63;
    fv4 v = *reinterpret_cast<const fv4*>(x + (size_t)(row0 + r) * IN_CH + k4 * 4);
    uint2 pk;
    pk.x = bfr(v.x) | (bfr(v.y) << 16);
    pk.y = bfr(v.z) | (bfr(v.w) << 16);
    unsigned off = (unsigned)(r * 512) + (((unsigned)(k4 * 8)) ^ ((unsigned)(r & 7) << 4));
    *reinterpret_cast<uint2*>(xs + off) = pk;
  }
#pragma unroll
  for (int it = 0; it < 16; ++it) {
    int f = it * 256 + tid;
    int col = f >> 5, ch = f & 31;
    bf16x8 v = *reinterpret_cast<const bf16x8*>(wt + (size_t)col * IN_CH + ch * 8);
    unsigned off = (unsigned)(col * 512) + (((unsigned)(ch * 16)) ^ ((unsigned)(col & 7) << 4));
    *reinterpret_cast<bf16x8*>(ws + off) = v;
  }
  __syncthreads();

  const int w = tid >> 6, l = tid & 63;
  const int lr = l & 15, lk = l >> 4;
  const int arow = (w & 1) * 16 + lr;
  const int cb = (w >> 1) * 64;

  f32x4 acc[4];
#pragma unroll
  for (int n = 0; n < 4; ++n) {
    int c0 = cb + n * 16 + lk * 4;
    acc[n] = (f32x4){b[c0], b[c0 + 1], b[c0 + 2], b[c0 + 3]};
  }

  const unsigned axm = (unsigned)(arow & 7) << 4;
#pragma unroll
  for (int kk = 0; kk < 8; ++kk) {
    bf16x8 af = *reinterpret_cast<const bf16x8*>(
        xs + (unsigned)(arow * 512) + (((unsigned)(kk * 64 + lk * 16)) ^ axm));
#pragma unroll
    for (int n = 0; n < 4; ++n) {
      int bcol = cb + n * 16 + lr;
      bf16x8 bf_ = *reinterpret_cast<const bf16x8*>(
          ws + (unsigned)(bcol * 512) +
          (((unsigned)(kk * 64 + lk * 16)) ^ ((unsigned)(bcol & 7) << 4)));
      acc[n] = __builtin_amdgcn_mfma_f32_16x16x32_bf16(bf_, af, acc[n], 0, 0, 0);
    }
  }

  const int grow = row0 + arow;
#pragma unroll
  for (int n = 0; n < 4; ++n) {
    int c0 = cb + n * 16 + lk * 4;
    uint2 pk;
    pk.x = bfr(acc[n][0]) | (bfr(acc[n][1]) << 16);
    pk.y = bfr(acc[n][2]) | (bfr(acc[n][3]) << 16);
    *reinterpret_cast<uint2*>(hb + (size_t)grow * OUT_CH + c0) = pk;
  }
}

// ---------------- histA: per-block bucket histogram (bucket-major out) -------
__global__ __launch_bounds__(256) void histA_kernel(
    const int* __restrict__ erow, int* __restrict__ histA) {
  __shared__ int hcnt[NBUCKET];
  const int blk = blockIdx.x, tid = threadIdx.x;
  for (int i = tid; i < NBUCKET; i += 256) hcnt[i] = 0;
  __syncthreads();
  const iv4* er4 = reinterpret_cast<const iv4*>(erow) + blk * CHUNK4;
  for (int i = tid; i < CHUNK4; i += 256) {
    iv4 r4 = __builtin_nontemporal_load(er4 + i);
    atomicAdd(&hcnt[r4.x >> 6], 1);
    atomicAdd(&hcnt[r4.y >> 6], 1);
    atomicAdd(&hcnt[r4.z >> 6], 1);
    atomicAdd(&hcnt[r4.w >> 6], 1);
  }
  __syncthreads();
  for (int b2 = tid; b2 < NBUCKET; b2 += 256) histA[b2 * NBLK + blk] = hcnt[b2];
}

// ---------------- 3-phase exclusive scan over NBUCKET*NBLK = 400128 ---------
__global__ __launch_bounds__(256) void scanA_partial(
    const int* __restrict__ a, int* __restrict__ bsum) {
  __shared__ int s[256];
  const int t = threadIdx.x;
  s[t] = a[blockIdx.x * 256 + t];
  __syncthreads();
#pragma unroll
  for (int d = 128; d > 0; d >>= 1) {
    if (t < d) s[t] += s[t + d];
    __syncthreads();
  }
  if (t == 0) bsum[blockIdx.x] = s[0];
}

// single block, 1024 thr, 2 elems/thread -> handles NBUCKET=1563
__global__ __launch_bounds__(1024) void scanA_bsums(int* __restrict__ bsum) {
  __shared__ int s[1024];
  const int t = threadIdx.x;
  const int i0 = 2 * t, i1 = 2 * t + 1;
  const int v0 = (i0 < NBUCKET) ? bsum[i0] : 0;
  const int v1 = (i1 < NBUCKET) ? bsum[i1] : 0;
  s[t] = v0 + v1;
  __syncthreads();
  for (int d = 1; d < 1024; d <<= 1) {
    int u = (t >= d) ? s[t - d] : 0;
    __syncthreads();
    s[t] += u;
    __syncthreads();
  }
  const int ex = (t == 0) ? 0 : s[t - 1];
  if (i0 < NBUCKET) bsum[i0] = ex;
  if (i1 < NBUCKET) bsum[i1] = ex + v0;
}

__global__ __launch_bounds__(256) void scanA_apply(
    int* __restrict__ a, const int* __restrict__ bsum) {
  __shared__ int s[256];
  const int t = threadIdx.x;
  const int idx = blockIdx.x * 256 + t;
  const int v = a[idx];
  s[t] = v;
  __syncthreads();
  for (int d = 1; d < 256; d <<= 1) {
    int u = (t >= d) ? s[t - d] : 0;
    __syncthreads();
    s[t] += u;
    __syncthreads();
  }
  a[idx] = s[t] - v + bsum[blockIdx.x];  // exclusive
}

// ---------------- scatterA: partition edges into bucket-major tmp ------------
__global__ __launch_bounds__(256) void scatterA_kernel(
    const int* __restrict__ erow, const int* __restrict__ ecol,
    const float* __restrict__ eval, const int* __restrict__ scanA,
    u64* __restrict__ tmp) {
  __shared__ int cur[NBUCKET];
  const int blk = blockIdx.x, tid = threadIdx.x;
  for (int b2 = tid; b2 < NBUCKET; b2 += 256) cur[b2] = scanA[b2 * NBLK + blk];
  __syncthreads();
  const iv4* er4 = reinterpret_cast<const iv4*>(erow) + blk * CHUNK4;
  const iv4* ec4 = reinterpret_cast<const iv4*>(ecol) + blk * CHUNK4;
  const fv4* ev4 = reinterpret_cast<const fv4*>(eval) + blk * CHUNK4;
  for (int i = tid; i < CHUNK4; i += 256) {
    iv4 r4 = __builtin_nontemporal_load(er4 + i);
    iv4 c4 = __builtin_nontemporal_load(ec4 + i);
    fv4 v4 = __builtin_nontemporal_load(ev4 + i);
#pragma unroll
    for (int j = 0; j < 4; ++j) {
      int r = r4[j];
      int pos = atomicAdd(&cur[r >> 6], 1);
      u64 q = ((u64)(unsigned)__float_as_int(v4[j]) << 32) |
              ((unsigned)(r & 63) << 17) | (unsigned)c4[j];
      __builtin_nontemporal_store(q, tmp + pos);
    }
  }
}

// ---------------- bucket_agg: in-LDS row sort + aggregate + store ------------
__global__ __launch_bounds__(AGG_T) void bucket_agg_kernel(
    const ushort_t* __restrict__ hb, const u64* __restrict__ tmp,
    const int* __restrict__ scanA, float* __restrict__ out) {
  __shared__ u64 eds[CAP];            // 22.5 KB sorted edges
  __shared__ int rcnt[RPB];
  __shared__ int rstart[RPB + 1];
  __shared__ int rcur[RPB];
  __shared__ int sscan[RPB];

  const int bkt = blockIdx.x, tid = threadIdx.x;
  const int base = scanA[bkt * NBLK];
  const int end = (bkt == NBUCKET - 1) ? N_EDGES : scanA[(bkt + 1) * NBLK];
  const int cnt = end - base;
  const int row0 = bkt * RPB;
  const unsigned* __restrict__ h32 = reinterpret_cast<const unsigned*>(hb);
  const int w = tid >> 6, lane = tid & 63;

  if (cnt <= CAP) {
    if (tid < RPB) rcnt[tid] = 0;
    __syncthreads();

    u64 qreg[QREG];
#pragma unroll
    for (int j = 0; j < QREG; ++j) {
      int i = j * AGG_T + tid;
      if (i < cnt) {
        qreg[j] = __builtin_nontemporal_load(tmp + base + i);
        atomicAdd(&rcnt[(unsigned)(qreg[j] >> 17) & 63u], 1);
      }
    }
    __syncthreads();

    // exclusive scan of 64 row counts
    if (tid < RPB) sscan[tid] = rcnt[tid];
    __syncthreads();
    for (int d = 1; d < RPB; d <<= 1) {
      int v = (tid < RPB && tid >= d) ? sscan[tid - d] : 0;
      __syncthreads();
      if (tid < RPB) sscan[tid] += v;
      __syncthreads();
    }
    if (tid < RPB) rstart[tid + 1] = sscan[tid];
    if (tid == 0) rstart[0] = 0;
    __syncthreads();
    if (tid < RPB) rcur[tid] = rstart[tid];
    __syncthreads();

#pragma unroll
    for (int j = 0; j < QREG; ++j) {
      int i = j * AGG_T + tid;
      if (i < cnt) {
        u64 q = qreg[j];
        int r = (unsigned)(q >> 17) & 63u;
        int pos = atomicAdd(&rcur[r], 1);
        eds[pos] = q;
      }
    }
    __syncthreads();

    // aggregate: wave w handles rows w, w+8, ... ; lane owns 2 channels
    for (int r = w; r < RPB; r += AGG_T / 64) {
      int grow = row0 + r;
      if (grow >= N_NODES) break;
      int e = rstart[r], e2 = rstart[r + 1];
      float ax = 0.f, ay = 0.f;
      for (; e + 3 < e2; e += 4) {
        u64 q0 = eds[e + 0], q1 = eds[e + 1];
        u64 q2 = eds[e + 2], q3 = eds[e + 3];
        unsigned u0 = h32[(size_t)(unsigned)(q0 & 0x1FFFFu) * 64 + lane];
        unsigned u1 = h32[(size_t)(unsigned)(q1 & 0x1FFFFu) * 64 + lane];
        unsigned u2 = h32[(size_t)(unsigned)(q2 & 0x1FFFFu) * 64 + lane];
        unsigned u3 = h32[(size_t)(unsigned)(q3 & 0x1FFFFu) * 64 + lane];
        float v0 = __int_as_float((int)(q0 >> 32));
        float v1 = __int_as_float((int)(q1 >> 32));
        float v2 = __int_as_float((int)(q2 >> 32));
        float v3 = __int_as_float((int)(q3 >> 32));
        ax += v0 * __uint_as_float(u0 << 16) + v1 * __uint_as_float(u1 << 16) +
              v2 * __uint_as_float(u2 << 16) + v3 * __uint_as_float(u3 << 16);
        ay += v0 * __uint_as_float(u0 & 0xFFFF0000u) +
              v1 * __uint_as_float(u1 & 0xFFFF0000u) +
              v2 * __uint_as_float(u2 & 0xFFFF0000u) +
              v3 * __uint_as_float(u3 & 0xFFFF0000u);
      }
      for (; e < e2; ++e) {
        u64 q = eds[e];
        unsigned u = h32[(size_t)(unsigned)(q & 0x1FFFFu) * 64 + lane];
        float v = __int_as_float((int)(q >> 32));
        ax += v * __uint_as_float(u << 16);
        ay += v * __uint_as_float(u & 0xFFFF0000u);
      }
      reinterpret_cast<float2*>(out)[(size_t)grow * 64 + lane] =
          make_float2(ax, ay);
    }
  } else {
    // fallback (statistically unreachable): zero rows then global atomics
    for (int i = tid; i < RPB * 64; i += AGG_T) {
      int grow = row0 + (i >> 6);
      if (grow < N_NODES)
        reinterpret_cast<float2*>(out)[(size_t)grow * 64 + (i & 63)] =
            make_float2(0.f, 0.f);
    }
    __syncthreads();
    for (int i = w; i < cnt; i += AGG_T / 64) {
      u64 q = tmp[base + i];
      int r = (unsigned)(q >> 17) & 63u;
      unsigned col = (unsigned)(q & 0x1FFFFu);
      float v = __int_as_float((int)(q >> 32));
      unsigned u = h32[(size_t)col * 64 + lane];
      if (row0 + r < N_NODES) {
        atomicAdd(out + (size_t)(row0 + r) * OUT_CH + lane * 2,
                  v * __uint_as_float(u << 16));
        atomicAdd(out + (size_t)(row0 + r) * OUT_CH + lane * 2 + 1,
                  v * __uint_as_float(u & 0xFFFF0000u));
      }
    }
  }
}

extern "C" void kernel_launch(void* const* d_in, const int* in_sizes, int n_in,
                              void* d_out, int out_size, void* d_ws,
                              size_t ws_size, hipStream_t stream) {
  const float* x    = (const float*)d_in[0];
  const float* W    = (const float*)d_in[1];
  const float* b    = (const float*)d_in[2];
  const int* erow   = (const int*)d_in[3];
  const int* ecol   = (const int*)d_in[4];
  const float* eval = (const float*)d_in[5];
  float* out = (float*)d_out;

  // Workspace (~52.9 MB):
  //   hb:    [0, 25.6MB)          N_NODES*OUT_CH bf16
  //   tmp:   [25.6MB, +25.6MB)    N_EDGES u64 (bucket-partitioned edges)
  //   scanA: [51.2MB, +1600512B)  NBUCKET*NBLK ints
  //   bsum:  [+6252B]             NBUCKET ints
  //   wt:    [+64KB]              W^T bf16 [128][256]
  char* wsb = (char*)d_ws;
  ushort_t* hb  = (ushort_t*)(wsb);
  u64* tmp      = (u64*)(wsb + 25600000);
  int* scanA    = (int*)(wsb + 51200000);
  int* bsum     = (int*)(wsb + 52800512);
  ushort_t* wt  = (ushort_t*)(wsb + 52806764 + 4);  // align 8

  // 1) h = x @ W + b  (bf16 MFMA)
  wt_prep_kernel<<<32, 256, 0, stream>>>(W, wt);
  gemm_mfma_kernel<<<N_NODES / GR, 256, 0, stream>>>(x, wt, b, hb);

  // 2) bucket partition (1563 buckets of 64 rows)
  histA_kernel<<<NBLK, 256, 0, stream>>>(erow, scanA);
  scanA_partial<<<NBUCKET, 256, 0, stream>>>(scanA, bsum);
  scanA_bsums<<<1, 1024, 0, stream>>>(bsum);
  scanA_apply<<<NBUCKET, 256, 0, stream>>>(scanA, bsum);
  scatterA_kernel<<<NBLK, 256, 0, stream>>>(erow, ecol, eval, scanA, tmp);

  // 3) fused in-LDS row-sort + aggregate + store
  bucket_agg_kernel<<<NBUCKET, AGG_T, 0, stream>>>(hb, tmp, scanA, out);
}

// Round 9
// 287.459 us; speedup vs baseline: 18.9138x; 1.0124x over previous
//
#include <hip/hip_runtime.h>
#include <hip/hip_bf16.h>

#define N_NODES 100000
#define N_EDGES 3200000
#define IN_CH   256
#define OUT_CH  128

#define RPB 64                      // rows per bucket
#define NBUCKET 1563                // ceil(100000/64)
#define NBLK 256                    // hist/scatter chunks (one per block)
#define PART_T 1024                 // hist/scatter threads per block
#define CHUNK (N_EDGES / NBLK)      // 12500 edges per block
#define CHUNK4 (CHUNK / 4)          // 3125 iv4 per block
#define CAP 2816                    // LDS edge cap per bucket (mu+17sigma)
#define AGG_T 512                   // bucket_agg threads
#define QREG 6                      // ceil(CAP/AGG_T)

typedef int   iv4 __attribute__((ext_vector_type(4)));
typedef float fv4 __attribute__((ext_vector_type(4)));
typedef short bf16x8 __attribute__((ext_vector_type(8)));
typedef float f32x4 __attribute__((ext_vector_type(4)));
typedef unsigned long long u64;
typedef unsigned short ushort_t;

// round-to-nearest-even f32 -> bf16 (as u16 in low bits)
__device__ __forceinline__ unsigned bfr(float f) {
  unsigned u = __float_as_uint(f);
  return (u + 0x7FFFu + ((u >> 16) & 1u)) >> 16;
}

// ---------------- W prep: wt[col][k] bf16 <- W[k][col] fp32 ------------------
__global__ __launch_bounds__(256) void wt_prep_kernel(
    const float* __restrict__ W, ushort_t* __restrict__ wt) {
  const int T = blockIdx.x * 256 + threadIdx.x;  // 0..8191
  const int col = T >> 6;
  const int k0 = (T & 63) * 4;
  uint2 pk;
  pk.x = bfr(W[(size_t)(k0 + 0) * OUT_CH + col]) |
         (bfr(W[(size_t)(k0 + 1) * OUT_CH + col]) << 16);
  pk.y = bfr(W[(size_t)(k0 + 2) * OUT_CH + col]) |
         (bfr(W[(size_t)(k0 + 3) * OUT_CH + col]) << 16);
  *reinterpret_cast<uint2*>(wt + (size_t)col * IN_CH + k0) = pk;
}

// ---------------- GEMM (MFMA bf16): hb = bf16(x @ W + b) ---------------------
#define GR 32

__global__ __launch_bounds__(256) void gemm_mfma_kernel(
    const float* __restrict__ x, const ushort_t* __restrict__ wt,
    const float* __restrict__ b, ushort_t* __restrict__ hb) {
  __shared__ alignas(16) char xs[GR * 512];    // 16 KB: [row][k]
  __shared__ alignas(16) char ws[128 * 512];   // 64 KB: [col][k]

  const int tid = threadIdx.x;
  const int row0 = blockIdx.x * GR;

#pragma unroll
  for (int it = 0; it < 8; ++it) {
    int f = it * 256 + tid;
    int r = f >> 6, k4 = f & 63;
    fv4 v = *reinterpret_cast<const fv4*>(x + (size_t)(row0 + r) * IN_CH + k4 * 4);
    uint2 pk;
    pk.x = bfr(v.x) | (bfr(v.y) << 16);
    pk.y = bfr(v.z) | (bfr(v.w) << 16);
    unsigned off = (unsigned)(r * 512) + (((unsigned)(k4 * 8)) ^ ((unsigned)(r & 7) << 4));
    *reinterpret_cast<uint2*>(xs + off) = pk;
  }
#pragma unroll
  for (int it = 0; it < 16; ++it) {
    int f = it * 256 + tid;
    int col = f >> 5, ch = f & 31;
    bf16x8 v = *reinterpret_cast<const bf16x8*>(wt + (size_t)col * IN_CH + ch * 8);
    unsigned off = (unsigned)(col * 512) + (((unsigned)(ch * 16)) ^ ((unsigned)(col & 7) << 4));
    *reinterpret_cast<bf16x8*>(ws + off) = v;
  }
  __syncthreads();

  const int w = tid >> 6, l = tid & 63;
  const int lr = l & 15, lk = l >> 4;
  const int arow = (w & 1) * 16 + lr;
  const int cb = (w >> 1) * 64;

  f32x4 acc[4];
#pragma unroll
  for (int n = 0; n < 4; ++n) {
    int c0 = cb + n * 16 + lk * 4;
    acc[n] = (f32x4){b[c0], b[c0 + 1], b[c0 + 2], b[c0 + 3]};
  }

  const unsigned axm = (unsigned)(arow & 7) << 4;
#pragma unroll
  for (int kk = 0; kk < 8; ++kk) {
    bf16x8 af = *reinterpret_cast<const bf16x8*>(
        xs + (unsigned)(arow * 512) + (((unsigned)(kk * 64 + lk * 16)) ^ axm));
#pragma unroll
    for (int n = 0; n < 4; ++n) {
      int bcol = cb + n * 16 + lr;
      bf16x8 bf_ = *reinterpret_cast<const bf16x8*>(
          ws + (unsigned)(bcol * 512) +
          (((unsigned)(kk * 64 + lk * 16)) ^ ((unsigned)(bcol & 7) << 4)));
      acc[n] = __builtin_amdgcn_mfma_f32_16x16x32_bf16(bf_, af, acc[n], 0, 0, 0);
    }
  }

  const int grow = row0 + arow;
#pragma unroll
  for (int n = 0; n < 4; ++n) {
    int c0 = cb + n * 16 + lk * 4;
    uint2 pk;
    pk.x = bfr(acc[n][0]) | (bfr(acc[n][1]) << 16);
    pk.y = bfr(acc[n][2]) | (bfr(acc[n][3]) << 16);
    *reinterpret_cast<uint2*>(hb + (size_t)grow * OUT_CH + c0) = pk;
  }
}

// ---------------- histA: per-block bucket histogram (bucket-major out) -------
__global__ __launch_bounds__(PART_T) void histA_kernel(
    const int* __restrict__ erow, int* __restrict__ histA) {
  __shared__ int hcnt[NBUCKET];
  const int blk = blockIdx.x, tid = threadIdx.x;
  for (int i = tid; i < NBUCKET; i += PART_T) hcnt[i] = 0;
  __syncthreads();
  const iv4* er4 = reinterpret_cast<const iv4*>(erow) + blk * CHUNK4;
  for (int i = tid; i < CHUNK4; i += PART_T) {
    iv4 r4 = __builtin_nontemporal_load(er4 + i);
    atomicAdd(&hcnt[r4.x >> 6], 1);
    atomicAdd(&hcnt[r4.y >> 6], 1);
    atomicAdd(&hcnt[r4.z >> 6], 1);
    atomicAdd(&hcnt[r4.w >> 6], 1);
  }
  __syncthreads();
  for (int b2 = tid; b2 < NBUCKET; b2 += PART_T)
    histA[b2 * NBLK + blk] = hcnt[b2];
}

// ---------------- 3-phase exclusive scan over NBUCKET*NBLK = 400128 ---------
__global__ __launch_bounds__(256) void scanA_partial(
    const int* __restrict__ a, int* __restrict__ bsum) {
  __shared__ int s[256];
  const int t = threadIdx.x;
  s[t] = a[blockIdx.x * 256 + t];
  __syncthreads();
#pragma unroll
  for (int d = 128; d > 0; d >>= 1) {
    if (t < d) s[t] += s[t + d];
    __syncthreads();
  }
  if (t == 0) bsum[blockIdx.x] = s[0];
}

// single block, 1024 thr, 2 elems/thread -> handles NBUCKET=1563
__global__ __launch_bounds__(1024) void scanA_bsums(int* __restrict__ bsum) {
  __shared__ int s[1024];
  const int t = threadIdx.x;
  const int i0 = 2 * t, i1 = 2 * t + 1;
  const int v0 = (i0 < NBUCKET) ? bsum[i0] : 0;
  const int v1 = (i1 < NBUCKET) ? bsum[i1] : 0;
  s[t] = v0 + v1;
  __syncthreads();
  for (int d = 1; d < 1024; d <<= 1) {
    int u = (t >= d) ? s[t - d] : 0;
    __syncthreads();
    s[t] += u;
    __syncthreads();
  }
  const int ex = (t == 0) ? 0 : s[t - 1];
  if (i0 < NBUCKET) bsum[i0] = ex;
  if (i1 < NBUCKET) bsum[i1] = ex + v0;
}

__global__ __launch_bounds__(256) void scanA_apply(
    int* __restrict__ a, const int* __restrict__ bsum) {
  __shared__ int s[256];
  const int t = threadIdx.x;
  const int idx = blockIdx.x * 256 + t;
  const int v = a[idx];
  s[t] = v;
  __syncthreads();
  for (int d = 1; d < 256; d <<= 1) {
    int u = (t >= d) ? s[t - d] : 0;
    __syncthreads();
    s[t] += u;
    __syncthreads();
  }
  a[idx] = s[t] - v + bsum[blockIdx.x];  // exclusive
}

// ---------------- scatterA: partition edges into bucket-major tmp ------------
__global__ __launch_bounds__(PART_T) void scatterA_kernel(
    const int* __restrict__ erow, const int* __restrict__ ecol,
    const float* __restrict__ eval, const int* __restrict__ scanA,
    u64* __restrict__ tmp) {
  __shared__ int cur[NBUCKET];
  const int blk = blockIdx.x, tid = threadIdx.x;
  for (int b2 = tid; b2 < NBUCKET; b2 += PART_T)
    cur[b2] = scanA[b2 * NBLK + blk];
  __syncthreads();
  const iv4* er4 = reinterpret_cast<const iv4*>(erow) + blk * CHUNK4;
  const iv4* ec4 = reinterpret_cast<const iv4*>(ecol) + blk * CHUNK4;
  const fv4* ev4 = reinterpret_cast<const fv4*>(eval) + blk * CHUNK4;
  for (int i = tid; i < CHUNK4; i += PART_T) {
    iv4 r4 = __builtin_nontemporal_load(er4 + i);
    iv4 c4 = __builtin_nontemporal_load(ec4 + i);
    fv4 v4 = __builtin_nontemporal_load(ev4 + i);
#pragma unroll
    for (int j = 0; j < 4; ++j) {
      int r = r4[j];
      int pos = atomicAdd(&cur[r >> 6], 1);
      u64 q = ((u64)(unsigned)__float_as_int(v4[j]) << 32) |
              ((unsigned)(r & 63) << 17) | (unsigned)c4[j];
      __builtin_nontemporal_store(q, tmp + pos);
    }
  }
}

// ---------------- bucket_agg: in-LDS row sort + aggregate + store ------------
__global__ __launch_bounds__(AGG_T) void bucket_agg_kernel(
    const ushort_t* __restrict__ hb, const u64* __restrict__ tmp,
    const int* __restrict__ scanA, float* __restrict__ out) {
  __shared__ u64 eds[CAP];            // 22.5 KB sorted edges
  __shared__ int rcnt[RPB];
  __shared__ int rstart[RPB + 1];
  __shared__ int rcur[RPB];
  __shared__ int sscan[RPB];

  const int bkt = blockIdx.x, tid = threadIdx.x;
  const int base = scanA[bkt * NBLK];
  const int end = (bkt == NBUCKET - 1) ? N_EDGES : scanA[(bkt + 1) * NBLK];
  const int cnt = end - base;
  const int row0 = bkt * RPB;
  const unsigned* __restrict__ h32 = reinterpret_cast<const unsigned*>(hb);
  const int w = tid >> 6, lane = tid & 63;

  if (cnt <= CAP) {
    if (tid < RPB) rcnt[tid] = 0;
    __syncthreads();

    u64 qreg[QREG];
#pragma unroll
    for (int j = 0; j < QREG; ++j) {
      int i = j * AGG_T + tid;
      if (i < cnt) {
        qreg[j] = __builtin_nontemporal_load(tmp + base + i);
        atomicAdd(&rcnt[(unsigned)(qreg[j] >> 17) & 63u], 1);
      }
    }
    __syncthreads();

    // exclusive scan of 64 row counts
    if (tid < RPB) sscan[tid] = rcnt[tid];
    __syncthreads();
    for (int d = 1; d < RPB; d <<= 1) {
      int v = (tid < RPB && tid >= d) ? sscan[tid - d] : 0;
      __syncthreads();
      if (tid < RPB) sscan[tid] += v;
      __syncthreads();
    }
    if (tid < RPB) rstart[tid + 1] = sscan[tid];
    if (tid == 0) rstart[0] = 0;
    __syncthreads();
    if (tid < RPB) rcur[tid] = rstart[tid];
    __syncthreads();

#pragma unroll
    for (int j = 0; j < QREG; ++j) {
      int i = j * AGG_T + tid;
      if (i < cnt) {
        u64 q = qreg[j];
        int r = (unsigned)(q >> 17) & 63u;
        int pos = atomicAdd(&rcur[r], 1);
        eds[pos] = q;
      }
    }
    __syncthreads();

    // aggregate: wave w handles rows w, w+8, ... ; lane owns 2 channels
    for (int r = w; r < RPB; r += AGG_T / 64) {
      int grow = row0 + r;
      if (grow >= N_NODES) break;
      int e = rstart[r], e2 = rstart[r + 1];
      float ax = 0.f, ay = 0.f;
      for (; e + 3 < e2; e += 4) {
        u64 q0 = eds[e + 0], q1 = eds[e + 1];
        u64 q2 = eds[e + 2], q3 = eds[e + 3];
        unsigned u0 = h32[(size_t)(unsigned)(q0 & 0x1FFFFu) * 64 + lane];
        unsigned u1 = h32[(size_t)(unsigned)(q1 & 0x1FFFFu) * 64 + lane];
        unsigned u2 = h32[(size_t)(unsigned)(q2 & 0x1FFFFu) * 64 + lane];
        unsigned u3 = h32[(size_t)(unsigned)(q3 & 0x1FFFFu) * 64 + lane];
        float v0 = __int_as_float((int)(q0 >> 32));
        float v1 = __int_as_float((int)(q1 >> 32));
        float v2 = __int_as_float((int)(q2 >> 32));
        float v3 = __int_as_float((int)(q3 >> 32));
        ax += v0 * __uint_as_float(u0 << 16) + v1 * __uint_as_float(u1 << 16) +
              v2 * __uint_as_float(u2 << 16) + v3 * __uint_as_float(u3 << 16);
        ay += v0 * __uint_as_float(u0 & 0xFFFF0000u) +
              v1 * __uint_as_float(u1 & 0xFFFF0000u) +
              v2 * __uint_as_float(u2 & 0xFFFF0000u) +
              v3 * __uint_as_float(u3 & 0xFFFF0000u);
      }
      for (; e < e2; ++e) {
        u64 q = eds[e];
        unsigned u = h32[(size_t)(unsigned)(q & 0x1FFFFu) * 64 + lane];
        float v = __int_as_float((int)(q >> 32));
        ax += v * __uint_as_float(u << 16);
        ay += v * __uint_as_float(u & 0xFFFF0000u);
      }
      reinterpret_cast<float2*>(out)[(size_t)grow * 64 + lane] =
          make_float2(ax, ay);
    }
  } else {
    // fallback (statistically unreachable): zero rows then global atomics
    for (int i = tid; i < RPB * 64; i += AGG_T) {
      int grow = row0 + (i >> 6);
      if (grow < N_NODES)
        reinterpret_cast<float2*>(out)[(size_t)grow * 64 + (i & 63)] =
            make_float2(0.f, 0.f);
    }
    __syncthreads();
    for (int i = w; i < cnt; i += AGG_T / 64) {
      u64 q = tmp[base + i];
      int r = (unsigned)(q >> 17) & 63u;
      unsigned col = (unsigned)(q & 0x1FFFFu);
      float v = __int_as_float((int)(q >> 32));
      unsigned u = h32[(size_t)col * 64 + lane];
      if (row0 + r < N_NODES) {
        atomicAdd(out + (size_t)(row0 + r) * OUT_CH + lane * 2,
                  v * __uint_as_float(u << 16));
        atomicAdd(out + (size_t)(row0 + r) * OUT_CH + lane * 2 + 1,
                  v * __uint_as_float(u & 0xFFFF0000u));
      }
    }
  }
}

extern "C" void kernel_launch(void* const* d_in, const int* in_sizes, int n_in,
                              void* d_out, int out_size, void* d_ws,
                              size_t ws_size, hipStream_t stream) {
  const float* x    = (const float*)d_in[0];
  const float* W    = (const float*)d_in[1];
  const float* b    = (const float*)d_in[2];
  const int* erow   = (const int*)d_in[3];
  const int* ecol   = (const int*)d_in[4];
  const float* eval = (const float*)d_in[5];
  float* out = (float*)d_out;

  // Workspace (~52.9 MB):
  //   hb:    [0, 25.6MB)          N_NODES*OUT_CH bf16
  //   tmp:   [25.6MB, +25.6MB)    N_EDGES u64 (bucket-partitioned edges)
  //   scanA: [51.2MB, +1600512B)  NBUCKET*NBLK ints
  //   bsum:  [+6252B]             NBUCKET ints
  //   wt:    [+64KB]              W^T bf16 [128][256]
  char* wsb = (char*)d_ws;
  ushort_t* hb  = (ushort_t*)(wsb);
  u64* tmp      = (u64*)(wsb + 25600000);
  int* scanA    = (int*)(wsb + 51200000);
  int* bsum     = (int*)(wsb + 52800512);
  ushort_t* wt  = (ushort_t*)(wsb + 52806764 + 4);  // align 8

  // 1) h = x @ W + b  (bf16 MFMA)
  wt_prep_kernel<<<32, 256, 0, stream>>>(W, wt);
  gemm_mfma_kernel<<<N_NODES / GR, 256, 0, stream>>>(x, wt, b, hb);

  // 2) bucket partition (1563 buckets of 64 rows); 16-wave blocks for latency
  histA_kernel<<<NBLK, PART_T, 0, stream>>>(erow, scanA);
  scanA_partial<<<NBUCKET, 256, 0, stream>>>(scanA, bsum);
  scanA_bsums<<<1, 1024, 0, stream>>>(bsum);
  scanA_apply<<<NBUCKET, 256, 0, stream>>>(scanA, bsum);
  scatterA_kernel<<<NBLK, PART_T, 0, stream>>>(erow, ecol, eval, scanA, tmp);

  // 3) fused in-LDS row-sort + aggregate + store
  bucket_agg_kernel<<<NBUCKET, AGG_T, 0, stream>>>(hb, tmp, scanA, out);
}

// Round 10
// 199.883 us; speedup vs baseline: 27.2006x; 1.4381x over previous
//
#include <hip/hip_runtime.h>
#include <hip/hip_bf16.h>

#define N_NODES 100000
#define N_EDGES 3200000
#define IN_CH   256
#define OUT_CH  128

#define RPB 64                      // rows per bucket
#define NBUCKET 1563                // ceil(100000/64)
#define NBLK 256                    // partition chunks (one per block)
#define PART_T 1024                 // histA threads per block
#define SS_T 1024                   // sortscatter threads per block
#define CHUNK (N_EDGES / NBLK)      // 12500 edges per block
#define CHUNK4 (CHUNK / 4)          // 3125 iv4 per block
#define CAP 2816                    // LDS edge cap per bucket (mu+17sigma)
#define AGG_T 512                   // bucket_agg threads
#define QREG 6                      // ceil(CAP/AGG_T)

typedef int   iv4 __attribute__((ext_vector_type(4)));
typedef float fv4 __attribute__((ext_vector_type(4)));
typedef short bf16x8 __attribute__((ext_vector_type(8)));
typedef float f32x4 __attribute__((ext_vector_type(4)));
typedef unsigned long long u64;
typedef unsigned short ushort_t;

// round-to-nearest-even f32 -> bf16 (as u16 in low bits)
__device__ __forceinline__ unsigned bfr(float f) {
  unsigned u = __float_as_uint(f);
  return (u + 0x7FFFu + ((u >> 16) & 1u)) >> 16;
}

// ---------------- W prep: wt[col][k] bf16 <- W[k][col] fp32 ------------------
__global__ __launch_bounds__(256) void wt_prep_kernel(
    const float* __restrict__ W, ushort_t* __restrict__ wt) {
  const int T = blockIdx.x * 256 + threadIdx.x;  // 0..8191
  const int col = T >> 6;
  const int k0 = (T & 63) * 4;
  uint2 pk;
  pk.x = bfr(W[(size_t)(k0 + 0) * OUT_CH + col]) |
         (bfr(W[(size_t)(k0 + 1) * OUT_CH + col]) << 16);
  pk.y = bfr(W[(size_t)(k0 + 2) * OUT_CH + col]) |
         (bfr(W[(size_t)(k0 + 3) * OUT_CH + col]) << 16);
  *reinterpret_cast<uint2*>(wt + (size_t)col * IN_CH + k0) = pk;
}

// ---------------- GEMM (MFMA bf16): hb = bf16(x @ W + b) ---------------------
#define GR 32

__global__ __launch_bounds__(256) void gemm_mfma_kernel(
    const float* __restrict__ x, const ushort_t* __restrict__ wt,
    const float* __restrict__ b, ushort_t* __restrict__ hb) {
  __shared__ alignas(16) char xs[GR * 512];    // 16 KB: [row][k]
  __shared__ alignas(16) char ws[128 * 512];   // 64 KB: [col][k]

  const int tid = threadIdx.x;
  const int row0 = blockIdx.x * GR;

#pragma unroll
  for (int it = 0; it < 8; ++it) {
    int f = it * 256 + tid;
    int r = f >> 6, k4 = f & 63;
    fv4 v = *reinterpret_cast<const fv4*>(x + (size_t)(row0 + r) * IN_CH + k4 * 4);
    uint2 pk;
    pk.x = bfr(v.x) | (bfr(v.y) << 16);
    pk.y = bfr(v.z) | (bfr(v.w) << 16);
    unsigned off = (unsigned)(r * 512) + (((unsigned)(k4 * 8)) ^ ((unsigned)(r & 7) << 4));
    *reinterpret_cast<uint2*>(xs + off) = pk;
  }
#pragma unroll
  for (int it = 0; it < 16; ++it) {
    int f = it * 256 + tid;
    int col = f >> 5, ch = f & 31;
    bf16x8 v = *reinterpret_cast<const bf16x8*>(wt + (size_t)col * IN_CH + ch * 8);
    unsigned off = (unsigned)(col * 512) + (((unsigned)(ch * 16)) ^ ((unsigned)(col & 7) << 4));
    *reinterpret_cast<bf16x8*>(ws + off) = v;
  }
  __syncthreads();

  const int w = tid >> 6, l = tid & 63;
  const int lr = l & 15, lk = l >> 4;
  const int arow = (w & 1) * 16 + lr;
  const int cb = (w >> 1) * 64;

  f32x4 acc[4];
#pragma unroll
  for (int n = 0; n < 4; ++n) {
    int c0 = cb + n * 16 + lk * 4;
    acc[n] = (f32x4){b[c0], b[c0 + 1], b[c0 + 2], b[c0 + 3]};
  }

  const unsigned axm = (unsigned)(arow & 7) << 4;
#pragma unroll
  for (int kk = 0; kk < 8; ++kk) {
    bf16x8 af = *reinterpret_cast<const bf16x8*>(
        xs + (unsigned)(arow * 512) + (((unsigned)(kk * 64 + lk * 16)) ^ axm));
#pragma unroll
    for (int n = 0; n < 4; ++n) {
      int bcol = cb + n * 16 + lr;
      bf16x8 bf_ = *reinterpret_cast<const bf16x8*>(
          ws + (unsigned)(bcol * 512) +
          (((unsigned)(kk * 64 + lk * 16)) ^ ((unsigned)(bcol & 7) << 4)));
      acc[n] = __builtin_amdgcn_mfma_f32_16x16x32_bf16(bf_, af, acc[n], 0, 0, 0);
    }
  }

  const int grow = row0 + arow;
#pragma unroll
  for (int n = 0; n < 4; ++n) {
    int c0 = cb + n * 16 + lk * 4;
    uint2 pk;
    pk.x = bfr(acc[n][0]) | (bfr(acc[n][1]) << 16);
    pk.y = bfr(acc[n][2]) | (bfr(acc[n][3]) << 16);
    *reinterpret_cast<uint2*>(hb + (size_t)grow * OUT_CH + c0) = pk;
  }
}

// ---------------- histA: per-block bucket histogram (bucket-major out) -------
__global__ __launch_bounds__(PART_T) void histA_kernel(
    const int* __restrict__ erow, int* __restrict__ histA) {
  __shared__ int hcnt[NBUCKET];
  const int blk = blockIdx.x, tid = threadIdx.x;
  for (int i = tid; i < NBUCKET; i += PART_T) hcnt[i] = 0;
  __syncthreads();
  const iv4* er4 = reinterpret_cast<const iv4*>(erow) + blk * CHUNK4;
  for (int i = tid; i < CHUNK4; i += PART_T) {
    iv4 r4 = __builtin_nontemporal_load(er4 + i);
    atomicAdd(&hcnt[r4.x >> 6], 1);
    atomicAdd(&hcnt[r4.y >> 6], 1);
    atomicAdd(&hcnt[r4.z >> 6], 1);
    atomicAdd(&hcnt[r4.w >> 6], 1);
  }
  __syncthreads();
  for (int b2 = tid; b2 < NBUCKET; b2 += PART_T)
    histA[b2 * NBLK + blk] = hcnt[b2];
}

// ---------------- 3-phase exclusive scan over NBUCKET*NBLK = 400128 ---------
__global__ __launch_bounds__(256) void scanA_partial(
    const int* __restrict__ a, int* __restrict__ bsum) {
  __shared__ int s[256];
  const int t = threadIdx.x;
  s[t] = a[blockIdx.x * 256 + t];
  __syncthreads();
#pragma unroll
  for (int d = 128; d > 0; d >>= 1) {
    if (t < d) s[t] += s[t + d];
    __syncthreads();
  }
  if (t == 0) bsum[blockIdx.x] = s[0];
}

// single block, 1024 thr, 2 elems/thread -> handles NBUCKET=1563
__global__ __launch_bounds__(1024) void scanA_bsums(int* __restrict__ bsum) {
  __shared__ int s[1024];
  const int t = threadIdx.x;
  const int i0 = 2 * t, i1 = 2 * t + 1;
  const int v0 = (i0 < NBUCKET) ? bsum[i0] : 0;
  const int v1 = (i1 < NBUCKET) ? bsum[i1] : 0;
  s[t] = v0 + v1;
  __syncthreads();
  for (int d = 1; d < 1024; d <<= 1) {
    int u = (t >= d) ? s[t - d] : 0;
    __syncthreads();
    s[t] += u;
    __syncthreads();
  }
  const int ex = (t == 0) ? 0 : s[t - 1];
  if (i0 < NBUCKET) bsum[i0] = ex;
  if (i1 < NBUCKET) bsum[i1] = ex + v0;
}

__global__ __launch_bounds__(256) void scanA_apply(
    int* __restrict__ a, const int* __restrict__ bsum) {
  __shared__ int s[256];
  const int t = threadIdx.x;
  const int idx = blockIdx.x * 256 + t;
  const int v = a[idx];
  s[t] = v;
  __syncthreads();
  for (int d = 1; d < 256; d <<= 1) {
    int u = (t >= d) ? s[t - d] : 0;
    __syncthreads();
    s[t] += u;
    __syncthreads();
  }
  a[idx] = s[t] - v + bsum[blockIdx.x];  // exclusive
}

// ---------------- sortscatter: local counting sort + monotone coalesced flush
// Per-block local sort of its 12500-edge chunk by bucket in LDS, then a linear
// flush where dst = i + delta[bkt[i]] is MONOTONE (scanA is bucket-major) ->
// adjacent lanes write adjacent tmp addresses -> full-line writes.
__global__ __launch_bounds__(SS_T) void sortscatter_kernel(
    const int* __restrict__ erow, const int* __restrict__ ecol,
    const float* __restrict__ eval, const int* __restrict__ scanA,
    u64* __restrict__ tmp) {
  __shared__ u64 sorted_q[CHUNK];        // 100000 B
  __shared__ ushort_t bkt[CHUNK];        // 25000 B
  __shared__ int cursor[NBUCKET];        // 6252 B (lstart -> running cursor)
  __shared__ int delta[NBUCKET];         // 6252 B

  const int blk = blockIdx.x, tid = threadIdx.x;
  int* sarr = reinterpret_cast<int*>(sorted_q);  // scan scratch (pre-scatter)

  // counts from adjacent differences of the scanned table (linear idx+1 is
  // the next segment in scan order; very last segment ends at N_EDGES)
  const int b0 = 2 * tid, b1 = 2 * tid + 1;
  int c0 = 0, c1 = 0, g0 = 0, g1 = 0;
  if (b0 < NBUCKET) {
    int idx = b0 * NBLK + blk;
    g0 = scanA[idx];
    int nxt = (idx + 1 < NBUCKET * NBLK) ? scanA[idx + 1] : N_EDGES;
    c0 = nxt - g0;
  }
  if (b1 < NBUCKET) {
    int idx = b1 * NBLK + blk;
    g1 = scanA[idx];
    int nxt = (idx + 1 < NBUCKET * NBLK) ? scanA[idx + 1] : N_EDGES;
    c1 = nxt - g1;
  }
  sarr[tid] = c0 + c1;
  __syncthreads();
  for (int d = 1; d < SS_T; d <<= 1) {
    int v = (tid >= d) ? sarr[tid - d] : 0;
    __syncthreads();
    sarr[tid] += v;
    __syncthreads();
  }
  const int pref = (tid == 0) ? 0 : sarr[tid - 1];
  __syncthreads();  // done with sarr (sorted_q reused below)
  if (b0 < NBUCKET) { cursor[b0] = pref;      delta[b0] = g0 - pref; }
  if (b1 < NBUCKET) { cursor[b1] = pref + c0; delta[b1] = g1 - (pref + c0); }
  __syncthreads();

  // scatter into LDS (the local sort)
  const iv4* er4 = reinterpret_cast<const iv4*>(erow) + blk * CHUNK4;
  const iv4* ec4 = reinterpret_cast<const iv4*>(ecol) + blk * CHUNK4;
  const fv4* ev4 = reinterpret_cast<const fv4*>(eval) + blk * CHUNK4;
  for (int i = tid; i < CHUNK4; i += SS_T) {
    iv4 r4 = __builtin_nontemporal_load(er4 + i);
    iv4 c4 = __builtin_nontemporal_load(ec4 + i);
    fv4 v4 = __builtin_nontemporal_load(ev4 + i);
#pragma unroll
    for (int j = 0; j < 4; ++j) {
      int r = r4[j];
      int bb = r >> 6;
      int pos = atomicAdd(&cursor[bb], 1);
      sorted_q[pos] = ((u64)(unsigned)__float_as_int(v4[j]) << 32) |
                      ((unsigned)(r & 63) << 17) | (unsigned)c4[j];
      bkt[pos] = (ushort_t)bb;
    }
  }
  __syncthreads();

  // monotone coalesced flush
  for (int i = tid; i < CHUNK; i += SS_T) {
    u64 q = sorted_q[i];
    int dst = i + delta[bkt[i]];
    __builtin_nontemporal_store(q, tmp + dst);
  }
}

// ---------------- bucket_agg: in-LDS row sort + aggregate + store ------------
__global__ __launch_bounds__(AGG_T) void bucket_agg_kernel(
    const ushort_t* __restrict__ hb, const u64* __restrict__ tmp,
    const int* __restrict__ scanA, float* __restrict__ out) {
  __shared__ u64 eds[CAP];            // 22.5 KB sorted edges
  __shared__ int rcnt[RPB];
  __shared__ int rstart[RPB + 1];
  __shared__ int rcur[RPB];
  __shared__ int sscan[RPB];

  const int bkt = blockIdx.x, tid = threadIdx.x;
  const int base = scanA[bkt * NBLK];
  const int end = (bkt == NBUCKET - 1) ? N_EDGES : scanA[(bkt + 1) * NBLK];
  const int cnt = end - base;
  const int row0 = bkt * RPB;
  const unsigned* __restrict__ h32 = reinterpret_cast<const unsigned*>(hb);
  const int w = tid >> 6, lane = tid & 63;

  if (cnt <= CAP) {
    if (tid < RPB) rcnt[tid] = 0;
    __syncthreads();

    u64 qreg[QREG];
#pragma unroll
    for (int j = 0; j < QREG; ++j) {
      int i = j * AGG_T + tid;
      if (i < cnt) {
        qreg[j] = __builtin_nontemporal_load(tmp + base + i);
        atomicAdd(&rcnt[(unsigned)(qreg[j] >> 17) & 63u], 1);
      }
    }
    __syncthreads();

    // exclusive scan of 64 row counts
    if (tid < RPB) sscan[tid] = rcnt[tid];
    __syncthreads();
    for (int d = 1; d < RPB; d <<= 1) {
      int v = (tid < RPB && tid >= d) ? sscan[tid - d] : 0;
      __syncthreads();
      if (tid < RPB) sscan[tid] += v;
      __syncthreads();
    }
    if (tid < RPB) rstart[tid + 1] = sscan[tid];
    if (tid == 0) rstart[0] = 0;
    __syncthreads();
    if (tid < RPB) rcur[tid] = rstart[tid];
    __syncthreads();

#pragma unroll
    for (int j = 0; j < QREG; ++j) {
      int i = j * AGG_T + tid;
      if (i < cnt) {
        u64 q = qreg[j];
        int r = (unsigned)(q >> 17) & 63u;
        int pos = atomicAdd(&rcur[r], 1);
        eds[pos] = q;
      }
    }
    __syncthreads();

    // aggregate: wave w handles rows w, w+8, ... ; lane owns 2 channels
    for (int r = w; r < RPB; r += AGG_T / 64) {
      int grow = row0 + r;
      if (grow >= N_NODES) break;
      int e = rstart[r], e2 = rstart[r + 1];
      float ax = 0.f, ay = 0.f;
      for (; e + 3 < e2; e += 4) {
        u64 q0 = eds[e + 0], q1 = eds[e + 1];
        u64 q2 = eds[e + 2], q3 = eds[e + 3];
        unsigned u0 = h32[(size_t)(unsigned)(q0 & 0x1FFFFu) * 64 + lane];
        unsigned u1 = h32[(size_t)(unsigned)(q1 & 0x1FFFFu) * 64 + lane];
        unsigned u2 = h32[(size_t)(unsigned)(q2 & 0x1FFFFu) * 64 + lane];
        unsigned u3 = h32[(size_t)(unsigned)(q3 & 0x1FFFFu) * 64 + lane];
        float v0 = __int_as_float((int)(q0 >> 32));
        float v1 = __int_as_float((int)(q1 >> 32));
        float v2 = __int_as_float((int)(q2 >> 32));
        float v3 = __int_as_float((int)(q3 >> 32));
        ax += v0 * __uint_as_float(u0 << 16) + v1 * __uint_as_float(u1 << 16) +
              v2 * __uint_as_float(u2 << 16) + v3 * __uint_as_float(u3 << 16);
        ay += v0 * __uint_as_float(u0 & 0xFFFF0000u) +
              v1 * __uint_as_float(u1 & 0xFFFF0000u) +
              v2 * __uint_as_float(u2 & 0xFFFF0000u) +
              v3 * __uint_as_float(u3 & 0xFFFF0000u);
      }
      for (; e < e2; ++e) {
        u64 q = eds[e];
        unsigned u = h32[(size_t)(unsigned)(q & 0x1FFFFu) * 64 + lane];
        float v = __int_as_float((int)(q >> 32));
        ax += v * __uint_as_float(u << 16);
        ay += v * __uint_as_float(u & 0xFFFF0000u);
      }
      reinterpret_cast<float2*>(out)[(size_t)grow * 64 + lane] =
          make_float2(ax, ay);
    }
  } else {
    // fallback (statistically unreachable): zero rows then global atomics
    for (int i = tid; i < RPB * 64; i += AGG_T) {
      int grow = row0 + (i >> 6);
      if (grow < N_NODES)
        reinterpret_cast<float2*>(out)[(size_t)grow * 64 + (i & 63)] =
            make_float2(0.f, 0.f);
    }
    __syncthreads();
    for (int i = w; i < cnt; i += AGG_T / 64) {
      u64 q = tmp[base + i];
      int r = (unsigned)(q >> 17) & 63u;
      unsigned col = (unsigned)(q & 0x1FFFFu);
      float v = __int_as_float((int)(q >> 32));
      unsigned u = h32[(size_t)col * 64 + lane];
      if (row0 + r < N_NODES) {
        atomicAdd(out + (size_t)(row0 + r) * OUT_CH + lane * 2,
                  v * __uint_as_float(u << 16));
        atomicAdd(out + (size_t)(row0 + r) * OUT_CH + lane * 2 + 1,
                  v * __uint_as_float(u & 0xFFFF0000u));
      }
    }
  }
}

extern "C" void kernel_launch(void* const* d_in, const int* in_sizes, int n_in,
                              void* d_out, int out_size, void* d_ws,
                              size_t ws_size, hipStream_t stream) {
  const float* x    = (const float*)d_in[0];
  const float* W    = (const float*)d_in[1];
  const float* b    = (const float*)d_in[2];
  const int* erow   = (const int*)d_in[3];
  const int* ecol   = (const int*)d_in[4];
  const float* eval = (const float*)d_in[5];
  float* out = (float*)d_out;

  // Workspace (~52.9 MB):
  //   hb:    [0, 25.6MB)          N_NODES*OUT_CH bf16
  //   tmp:   [25.6MB, +25.6MB)    N_EDGES u64 (bucket-partitioned edges)
  //   scanA: [51.2MB, +1600512B)  NBUCKET*NBLK ints
  //   bsum:  [+6252B]             NBUCKET ints
  //   wt:    [+64KB]              W^T bf16 [128][256]
  char* wsb = (char*)d_ws;
  ushort_t* hb  = (ushort_t*)(wsb);
  u64* tmp      = (u64*)(wsb + 25600000);
  int* scanA    = (int*)(wsb + 51200000);
  int* bsum     = (int*)(wsb + 52800512);
  ushort_t* wt  = (ushort_t*)(wsb + 52806764 + 4);  // align 8

  // 1) h = x @ W + b  (bf16 MFMA)
  wt_prep_kernel<<<32, 256, 0, stream>>>(W, wt);
  gemm_mfma_kernel<<<N_NODES / GR, 256, 0, stream>>>(x, wt, b, hb);

  // 2) bucket partition (1563 buckets of 64 rows)
  histA_kernel<<<NBLK, PART_T, 0, stream>>>(erow, scanA);
  scanA_partial<<<NBUCKET, 256, 0, stream>>>(scanA, bsum);
  scanA_bsums<<<1, 1024, 0, stream>>>(bsum);
  scanA_apply<<<NBUCKET, 256, 0, stream>>>(scanA, bsum);
  sortscatter_kernel<<<NBLK, SS_T, 0, stream>>>(erow, ecol, eval, scanA, tmp);

  // 3) fused in-LDS row-sort + aggregate + store
  bucket_agg_kernel<<<NBUCKET, AGG_T, 0, stream>>>(hb, tmp, scanA, out);
}